// Round 2
// baseline (545.701 us; speedup 1.0000x reference)
//
#include <hip/hip_runtime.h>
#include <math.h>
#include <utility>

typedef __attribute__((ext_vector_type(8))) short    bf16x8;
typedef __attribute__((ext_vector_type(4))) float    f32x4;
typedef __attribute__((ext_vector_type(2))) float    f32x2;
typedef __attribute__((ext_vector_type(2))) unsigned u32x2;
typedef __attribute__((ext_vector_type(4))) unsigned u32x4;

template<int I, int N, class F>
__device__ __forceinline__ void sfor(F&& f) {
    if constexpr (I < N) { f(std::integral_constant<int, I>{}); sfor<I + 1, N>(static_cast<F&&>(f)); }
}

#define NPT    50000
#define NTILES 6250     // 400000 pts / 64 per tile, exact
#define TPB    2        // tiles per block
#define Z_S    128      // shorts per z1/z2 row (256 B), XOR-swizzled 16B columns
#define LOG2E  1.4426950408889634f

static __device__ __forceinline__ unsigned short bf16r(float f) {   // RNE f32->bf16
    unsigned u = __builtin_bit_cast(unsigned, f);
    u += 0x7FFFu + ((u >> 16) & 1u);
    return (unsigned short)(u >> 16);
}

#if defined(__has_builtin)
#if __has_builtin(__builtin_amdgcn_cvt_pk_bf16_f32)
#define HAVE_CVT_PK_BF16 1
#endif
#if __has_builtin(__builtin_amdgcn_exp2f) && __has_builtin(__builtin_amdgcn_rcpf)
#define HAVE_RAW_TRANS 1
#endif
#endif

static __device__ __forceinline__ unsigned packbf(float a, float b) {
#ifdef HAVE_CVT_PK_BF16
    return __builtin_bit_cast(unsigned, __builtin_amdgcn_cvt_pk_bf16_f32(a, b));
#else
    return (unsigned)bf16r(a) | ((unsigned)bf16r(b) << 16);
#endif
}

#ifdef HAVE_RAW_TRANS
static __device__ __forceinline__ float fexp2(float x) { return __builtin_amdgcn_exp2f(x); }
static __device__ __forceinline__ float frcp(float x)  { return __builtin_amdgcn_rcpf(x); }
#else
static __device__ __forceinline__ float fexp2(float x) { return __exp2f(x); }
static __device__ __forceinline__ float frcp(float x)  { return __frcp_rn(x); }
#endif

// paired gated activation, packed-f32 form. g pre-scaled by -log2e so
// sigma_i = 1/(1 + 2^gp_i); one shared v_rcp via reciprocal-product; the
// add/mul/max run as v_pk_*_f32 (float2 ext-vector ops), .yx swizzle folds
// into op_sel. p in (1, 2^~45] -> no overflow, no NaN.
static __device__ __forceinline__ unsigned gate2p(f32x2 h, f32x2 gp) {
    f32x2 e;
    e.x = fexp2(gp.x);
    e.y = fexp2(gp.y);
    f32x2 p = e + 1.f;                                   // v_pk_add_f32
    float ip = frcp(p.x * p.y);
    f32x2 ps = __builtin_shufflevector(p, p, 1, 0);      // op_sel swizzle
    f32x2 z = (h * ps) * ip;                             // v_pk_mul_f32 x2
    z = __builtin_elementwise_max(z, f32x2{0.f, 0.f});   // v_pk_max_f32
    return packbf(z.x, z.y);
}

static __device__ __forceinline__ bf16x8 pack8s(const float* p, float s) { // p 16B-aligned
    f32x4 lo = *reinterpret_cast<const f32x4*>(p);
    f32x4 hi = *reinterpret_cast<const f32x4*>(p + 4);
    u32x4 u = { packbf(lo[0]*s, lo[1]*s), packbf(lo[2]*s, lo[3]*s),
                packbf(hi[0]*s, hi[1]*s), packbf(hi[2]*s, hi[3]*s) };
    return __builtin_bit_cast(bf16x8, u);
}
static __device__ __forceinline__ f32x4 mfma16(bf16x8 a, bf16x8 b, f32x4 c) {
    return __builtin_amdgcn_mfma_f32_16x16x32_bf16(a, b, c, 0, 0, 0);
}

// Block = 512 thr = 8 waves, TWO 64-point tiles per block (preload amortized).
// Wave w owns channel rows [16w,16w+16); waves 0-3 own points [16w,16w+16).
// Round-13 (resubmit; R1 bench was an infra failure): LDS diet 48.6K -> 38.7K
// for 4 blocks/CU (launch_bounds(512,8)):
//   - z1/z2 rows 136->128 shorts, +XOR swizzle c^=(row&7) on 16B cols
//     (even/odd-ks split bases keep per-access VALU at zero)
//   - zin rows 80B->16B: only k<8 ever multiplied by nonzero A; q>0 lanes
//     broadcast-read the q==0 row (finite * 0 = 0)
//   - aow compacted to the 3 real output rows (m>=3 lanes clamp to row 2;
//     their C rows are never read)
__global__ __launch_bounds__(512, 8) void node_rk4_mfma(
    const float* __restrict__ x0,
    const float* __restrict__ h1_w, const float* __restrict__ h1_b,
    const float* __restrict__ g1_w, const float* __restrict__ g1_b,
    const float* __restrict__ h2_w, const float* __restrict__ h2_b,
    const float* __restrict__ g2_w, const float* __restrict__ g2_b,
    const float* __restrict__ out_w, const float* __restrict__ out_b,
    float* __restrict__ y)
{
    __shared__ __align__(16) short zin[64 * 8];          // 1 KiB, k=0..7 per point
    __shared__ __align__(16) short z1s[64 * Z_S];        // 16 KiB
    __shared__ __align__(16) short z2s[64 * Z_S];        // 16 KiB
    __shared__ __align__(16) short aow_s[4 * 12 * 8];    // out A-frags [ks][mrow<3][q]
    __shared__ __align__(16) float bias_s[4 * 128 + 16]; // h1,g1',h2,g2' + vob'
    __shared__ __align__(8)  unsigned a1_s[2 * 256];     // layer1 A rows (h, g')

    const int tid  = threadIdx.x;
    const int w    = tid >> 6;        // wave id 0..7
    const int lane = tid & 63;
    const int q    = lane >> 4;       // quad 0..3
    const int m    = lane & 15;       // MFMA row (A) / col (B,C)

    // ---------------- weight preload (once per block, reused by TPB tiles) ----
    const int row = 16 * w + m;                 // this lane's A-row (channel)
    bf16x8 a2h[4], a2g[4];                      // layer2 A-frags per k-step (32 regs)
    sfor<0, 4>([&](auto KS) {
        constexpr int ks = KS.value;
        a2h[ks] = pack8s(h2_w + row * 128 + ks * 32 + q * 8, 1.0f);
        a2g[ks] = pack8s(g2_w + row * 128 + ks * 32 + q * 8, -LOG2E);
    });
    // layer1 A rows -> LDS compact (4 bf16 = 8 B per channel, h then g)
    if (tid < 128) {
        const f32x4 t1 = *reinterpret_cast<const f32x4*>(h1_w + tid * 4);
        const f32x4 t2 = *reinterpret_cast<const f32x4*>(g1_w + tid * 4);
        a1_s[tid * 2]           = packbf(t1[0], t1[1]);
        a1_s[tid * 2 + 1]       = packbf(t1[2], t1[3]);
        a1_s[256 + tid * 2]     = packbf(t2[0] * -LOG2E, t2[1] * -LOG2E);
        a1_s[256 + tid * 2 + 1] = packbf(t2[2] * -LOG2E, t2[3] * -LOG2E);
    }
    // out-layer A-frags -> LDS, compact: only real rows m<3 stored
    if (w == 0 && m < 3) {
        sfor<0, 4>([&](auto KS) {
            constexpr int ks = KS.value;
            bf16x8 t = pack8s(out_w + m * 128 + ks * 32 + q * 8, 2.f * LOG2E);
            *reinterpret_cast<bf16x8*>(&aow_s[((ks * 3 + m) * 4 + q) * 8]) = t;
        });
    }
    // biases -> LDS (C-frag reads are wave-broadcast)
    if (tid < 128) {
        bias_s[tid]       = h1_b[tid];
        bias_s[128 + tid] = g1_b[tid] * -LOG2E;
        bias_s[256 + tid] = h2_b[tid];
        bias_s[384 + tid] = g2_b[tid] * -LOG2E;
    }
    if (tid < 16) bias_s[512 + tid] = (tid < 3) ? out_b[tid] * (2.f * LOG2E) : 0.f;

    // zero zin once: shorts 4..7 of each row must stay 0 (A is 0 for k>=4,
    // but 0 * NaN-pattern garbage would poison the MFMA)
    if (tid < 64) *reinterpret_cast<u32x4*>(&zin[tid * 8]) = u32x4{0u, 0u, 0u, 0u};
    __syncthreads();

    const float third = 1.0f / 3.0f;
    const int cb4 = 16 * w + 4 * q;   // this lane's C-frag channel base

    // swizzle helpers: element (row r, 16B-col c) lives at col c ^ (r&7).
    // Row index never changes r&7 across nt (nt*16 rows), so the XOR folds
    // entirely into two base pointers: even-ks and odd-ks.
    const int m7   = m & 7;
    const int qx8  = (q ^ (m & 3)) * 8;     // q-part of swizzled col, shorts
    const int m4_8 = (m & 4) * 8;           // ks-part toggle, shorts

    // hoisted per-lane LDS base pointers (stage/tile-invariant)
    const short* zin_rd = &zin[m * 8];                    // + nt*128 (all lanes; q>0 bcast)
    short*       zin_wr = &zin[row * 8];                  // lanes<16, w<4
    const short* z1_re  = &z1s[m * Z_S + qx8 + m4_8];         // even ks: +nt*2048 +ks*32
    const short* z1_ro  = &z1s[m * Z_S + qx8 + (m4_8 ^ 32)];  // odd ks: +nt*2048 +(ks-1)*32
    short*       z1_wr  = &z1s[m * Z_S + (((2 * w + (q >> 1)) ^ m7) * 8) + (q & 1) * 4];
    short*       z2_wr  = &z2s[m * Z_S + (((2 * w + (q >> 1)) ^ m7) * 8) + (q & 1) * 4];
    const short* z2_re  = &z2s[(16 * w + m) * Z_S + qx8 + m4_8];        // w<4, +ks*32
    const short* z2_ro  = &z2s[(16 * w + m) * Z_S + qx8 + (m4_8 ^ 32)];
    const short* aow_rd = &aow_s[((m < 3 ? m : 2) * 4 + q) * 8];        // + ks*96
    const float* bs     = &bias_s[cb4];                   // +0,+128,+256,+384
    const float* bsov   = &bias_s[512 + 4 * q];

    #pragma unroll 1
    for (int t2 = 0; t2 < TPB; ++t2) {
        const int tile = blockIdx.x * TPB + t2;

        // RK4 state: waves 0-3, lanes 0-15 (point = tile*64 + w*16 + lane)
        float xc0 = 0.f, xc1 = 0.f, xc2 = 0.f;
        int gbase = 0;
        if (w < 4 && lane < 16) {
            const int pg = tile * 64 + w * 16 + lane;
            const int bb = pg / NPT;
            const int nn = pg - bb * NPT;
            gbase = bb * 3 * NPT + nn;
            xc0 = x0[gbase]; xc1 = x0[gbase + NPT]; xc2 = x0[gbase + 2 * NPT];
        }
        float k1x=0,k1y=0,k1z=0, k2x=0,k2y=0,k2z=0, k3x=0,k3y=0,k3z=0;
        float ax=0, ay=0, az=0;

        #pragma unroll 1
        for (int s = 0; s < 4; ++s) {
            // ---- stage input -> zin (B-frag rows; owner lanes only) ----
            if (w < 4 && lane < 16) {
                float zi0, zi1, zi2, tt;
                if (s == 0)      { zi0 = xc0; zi1 = xc1; zi2 = xc2; tt = 0.f; }
                else if (s == 1) { zi0 = fmaf(k1x, third, xc0);
                                   zi1 = fmaf(k1y, third, xc1);
                                   zi2 = fmaf(k1z, third, xc2); tt = third; }
                else if (s == 2) { zi0 = xc0 + (k2x - k1x * third);
                                   zi1 = xc1 + (k2y - k1y * third);
                                   zi2 = xc2 + (k2z - k1z * third); tt = 2.f * third; }
                else             { zi0 = xc0 + (k1x - k2x + k3x);
                                   zi1 = xc1 + (k1y - k2y + k3y);
                                   zi2 = xc2 + (k1z - k2z + k3z); tt = 1.f; }
                u32x2 pk = { packbf(zi0, zi1), packbf(zi2, tt) };
                *reinterpret_cast<u32x2*>(zin_wr) = pk;
            }
            __syncthreads();

            // ---- layer 1 (4->128, K-padded MFMA); A-frags rebuilt from LDS ----
            {
                bf16x8 a1h = {0,0,0,0,0,0,0,0}, a1g = {0,0,0,0,0,0,0,0};
                if (q == 0) {
                    u32x2 th = *reinterpret_cast<const u32x2*>(&a1_s[row * 2]);
                    u32x2 tg = *reinterpret_cast<const u32x2*>(&a1_s[256 + row * 2]);
                    u32x4 uh = { th[0], th[1], 0u, 0u };
                    u32x4 ug = { tg[0], tg[1], 0u, 0u };
                    a1h = __builtin_bit_cast(bf16x8, uh);
                    a1g = __builtin_bit_cast(bf16x8, ug);
                }
                const f32x4 b1h = *reinterpret_cast<const f32x4*>(bs);
                const f32x4 b1g = *reinterpret_cast<const f32x4*>(bs + 128);
                sfor<0, 4>([&](auto NT) {
                    constexpr int nt = NT.value;
                    bf16x8 bf = *reinterpret_cast<const bf16x8*>(zin_rd + nt * 128);
                    f32x4 ch = mfma16(a1h, bf, b1h);
                    f32x4 cg = mfma16(a1g, bf, b1g);
                    u32x2 pk = { gate2p(f32x2{ch[0], ch[1]}, f32x2{cg[0], cg[1]}),
                                 gate2p(f32x2{ch[2], ch[3]}, f32x2{cg[2], cg[3]}) };
                    *reinterpret_cast<u32x2*>(z1_wr + nt * 2048) = pk;
                });
            }
            __syncthreads();

            // ---- layer 2 (128->128); fully unrolled, bias rides in as C ----
            {
                const f32x4 b2h = *reinterpret_cast<const f32x4*>(bs + 256);
                const f32x4 b2g = *reinterpret_cast<const f32x4*>(bs + 384);
                f32x4 ch[4], cg[4];
                sfor<0, 4>([&](auto NT) {
                    constexpr int nt = NT.value;
                    bf16x8 bf = *reinterpret_cast<const bf16x8*>(z1_re + nt * 2048);
                    ch[nt] = mfma16(a2h[0], bf, b2h);
                    cg[nt] = mfma16(a2g[0], bf, b2g);
                });
                sfor<1, 4>([&](auto KS) {
                    constexpr int ks = KS.value;
                    const short* zb = (ks & 1) ? z1_ro : z1_re;
                    constexpr int koff = (ks & 2) ? 64 : 0;
                    sfor<0, 4>([&](auto NT) {
                        constexpr int nt = NT.value;
                        bf16x8 bf = *reinterpret_cast<const bf16x8*>(zb + nt * 2048 + koff);
                        ch[nt] = mfma16(a2h[ks], bf, ch[nt]);
                        cg[nt] = mfma16(a2g[ks], bf, cg[nt]);
                    });
                });
                sfor<0, 4>([&](auto NT) {
                    constexpr int nt = NT.value;
                    u32x2 pk = { gate2p(f32x2{ch[nt][0], ch[nt][1]}, f32x2{cg[nt][0], cg[nt][1]}),
                                 gate2p(f32x2{ch[nt][2], ch[nt][3]}, f32x2{cg[nt][2], cg[nt][3]}) };
                    *reinterpret_cast<u32x2*>(z2_wr + nt * 2048) = pk;
                });
            }
            __syncthreads();

            // ---- out layer (128->3, M padded to 16); waves 0-3, 16 pts each ----
            if (w < 4) {
                f32x4 vc = *reinterpret_cast<const f32x4*>(bsov);
                sfor<0, 4>([&](auto KS) {
                    constexpr int ks = KS.value;
                    bf16x8 af = *reinterpret_cast<const bf16x8*>(aow_rd + ks * 96);
                    const short* zb = (ks & 1) ? z2_ro : z2_re;
                    constexpr int koff = (ks & 2) ? 64 : 0;
                    bf16x8 bf = *reinterpret_cast<const bf16x8*>(zb + koff);
                    vc = mfma16(af, bf, vc);
                });
                // khalf = tanh*0.5 = 0.5 - 1/p, p = 2^v' + 1 (scale folded into
                // out weights). Pair kx,ky through one rcp (packed add); kz single.
                f32x2 e; e.x = fexp2(vc[0]); e.y = fexp2(vc[1]);
                f32x2 p = e + 1.f;
                const float ipxy = frcp(p.x * p.y);
                const float kx = 0.5f - p.y * ipxy;
                const float ky = 0.5f - p.x * ipxy;
                const float kz = 0.5f - frcp(fexp2(vc[2]) + 1.f);

                if (s == 0)      { k1x=kx;k1y=ky;k1z=kz; ax=kx;ay=ky;az=kz; }
                else if (s == 1) { k2x=kx;k2y=ky;k2z=kz;
                                   ax=fmaf(3.f,kx,ax); ay=fmaf(3.f,ky,ay); az=fmaf(3.f,kz,az); }
                else if (s == 2) { k3x=kx;k3y=ky;k3z=kz;
                                   ax=fmaf(3.f,kx,ax); ay=fmaf(3.f,ky,ay); az=fmaf(3.f,kz,az); }
                else             { ax+=kx; ay+=ky; az+=kz; }
            }
        }

        if (w < 4 && lane < 16) {
            y[gbase]           = fmaf(0.125f, ax, xc0);
            y[gbase + NPT]     = fmaf(0.125f, ay, xc1);
            y[gbase + 2 * NPT] = fmaf(0.125f, az, xc2);
        }
        __syncthreads();   // zin/z1/z2 reuse safety across tiles
    }
}

extern "C" void kernel_launch(void* const* d_in, const int* in_sizes, int n_in,
                              void* d_out, int out_size, void* d_ws, size_t ws_size,
                              hipStream_t stream) {
    (void)in_sizes; (void)n_in; (void)d_ws; (void)ws_size; (void)out_size;
    const float* x0    = (const float*)d_in[0];
    const float* h1_w  = (const float*)d_in[1];
    const float* h1_b  = (const float*)d_in[2];
    const float* g1_w  = (const float*)d_in[3];
    const float* g1_b  = (const float*)d_in[4];
    const float* h2_w  = (const float*)d_in[5];
    const float* h2_b  = (const float*)d_in[6];
    const float* g2_w  = (const float*)d_in[7];
    const float* g2_b  = (const float*)d_in[8];
    const float* out_w = (const float*)d_in[9];
    const float* out_b = (const float*)d_in[10];
    float* y = (float*)d_out;

    // two 64-pt tiles per 512-thread block
    node_rk4_mfma<<<NTILES / TPB, 512, 0, stream>>>(
        x0, h1_w, h1_b, g1_w, g1_b, h2_w, h2_b, g2_w, g2_b, out_w, out_b, y);
}

// Round 3
// 292.854 us; speedup vs baseline: 1.8634x; 1.8634x over previous
//
#include <hip/hip_runtime.h>
#include <math.h>
#include <utility>

typedef __attribute__((ext_vector_type(8))) short    bf16x8;
typedef __attribute__((ext_vector_type(4))) float    f32x4;
typedef __attribute__((ext_vector_type(2))) float    f32x2;
typedef __attribute__((ext_vector_type(2))) unsigned u32x2;
typedef __attribute__((ext_vector_type(4))) unsigned u32x4;

template<int I, int N, class F>
__device__ __forceinline__ void sfor(F&& f) {
    if constexpr (I < N) { f(std::integral_constant<int, I>{}); sfor<I + 1, N>(static_cast<F&&>(f)); }
}

#define NPT    50000
#define NTILES 6250     // 400000 pts / 64 per tile, exact
#define TPB    2        // tiles per block
#define Z_S    128      // shorts per z1/z2 row (256 B), XOR-swizzled 16B columns
#define LOG2E  1.4426950408889634f

static __device__ __forceinline__ unsigned short bf16r(float f) {   // RNE f32->bf16
    unsigned u = __builtin_bit_cast(unsigned, f);
    u += 0x7FFFu + ((u >> 16) & 1u);
    return (unsigned short)(u >> 16);
}

#if defined(__has_builtin)
#if __has_builtin(__builtin_amdgcn_cvt_pk_bf16_f32)
#define HAVE_CVT_PK_BF16 1
#endif
#if __has_builtin(__builtin_amdgcn_exp2f) && __has_builtin(__builtin_amdgcn_rcpf)
#define HAVE_RAW_TRANS 1
#endif
#endif

static __device__ __forceinline__ unsigned packbf(float a, float b) {
#ifdef HAVE_CVT_PK_BF16
    return __builtin_bit_cast(unsigned, __builtin_amdgcn_cvt_pk_bf16_f32(a, b));
#else
    return (unsigned)bf16r(a) | ((unsigned)bf16r(b) << 16);
#endif
}

#ifdef HAVE_RAW_TRANS
static __device__ __forceinline__ float fexp2(float x) { return __builtin_amdgcn_exp2f(x); }
static __device__ __forceinline__ float frcp(float x)  { return __builtin_amdgcn_rcpf(x); }
#else
static __device__ __forceinline__ float fexp2(float x) { return __exp2f(x); }
static __device__ __forceinline__ float frcp(float x)  { return __frcp_rn(x); }
#endif

// paired gated activation, packed-f32 form. g pre-scaled by -log2e so
// sigma_i = 1/(1 + 2^gp_i); one shared v_rcp via reciprocal-product; the
// add/mul/max run as v_pk_*_f32 (float2 ext-vector ops), .yx swizzle folds
// into op_sel. p in (1, 2^~45] -> no overflow, no NaN.
static __device__ __forceinline__ unsigned gate2p(f32x2 h, f32x2 gp) {
    f32x2 e;
    e.x = fexp2(gp.x);
    e.y = fexp2(gp.y);
    f32x2 p = e + 1.f;                                   // v_pk_add_f32
    float ip = frcp(p.x * p.y);
    f32x2 ps = __builtin_shufflevector(p, p, 1, 0);      // op_sel swizzle
    f32x2 z = (h * ps) * ip;                             // v_pk_mul_f32 x2
    z = __builtin_elementwise_max(z, f32x2{0.f, 0.f});   // v_pk_max_f32
    return packbf(z.x, z.y);
}

static __device__ __forceinline__ bf16x8 pack8s(const float* p, float s) { // p 16B-aligned
    f32x4 lo = *reinterpret_cast<const f32x4*>(p);
    f32x4 hi = *reinterpret_cast<const f32x4*>(p + 4);
    u32x4 u = { packbf(lo[0]*s, lo[1]*s), packbf(lo[2]*s, lo[3]*s),
                packbf(hi[0]*s, hi[1]*s), packbf(hi[2]*s, hi[3]*s) };
    return __builtin_bit_cast(bf16x8, u);
}
static __device__ __forceinline__ f32x4 mfma16(bf16x8 a, bf16x8 b, f32x4 c) {
    return __builtin_amdgcn_mfma_f32_16x16x32_bf16(a, b, c, 0, 0, 0);
}

// Block = 512 thr = 8 waves, TWO 64-point tiles per block (preload amortized).
// Wave w owns channel rows [16w,16w+16); waves 0-3 own points [16w,16w+16).
// Round-14: R13 LDS diet (38.9K) kept, launch bound reverted (512,8)->(512,4).
// R2 post-mortem: forcing 8 waves/EU clamps unified regs to 64 < ~90 live ->
// 1.9 GB scratch spill traffic, 2x regression. Registers are the occupancy
// limiter for this structure; let the allocator breathe and take the 4th
// block/CU only if the natural allocation permits it.
__global__ __launch_bounds__(512, 4) void node_rk4_mfma(
    const float* __restrict__ x0,
    const float* __restrict__ h1_w, const float* __restrict__ h1_b,
    const float* __restrict__ g1_w, const float* __restrict__ g1_b,
    const float* __restrict__ h2_w, const float* __restrict__ h2_b,
    const float* __restrict__ g2_w, const float* __restrict__ g2_b,
    const float* __restrict__ out_w, const float* __restrict__ out_b,
    float* __restrict__ y)
{
    __shared__ __align__(16) short zin[64 * 8];          // 1 KiB, k=0..7 per point
    __shared__ __align__(16) short z1s[64 * Z_S];        // 16 KiB
    __shared__ __align__(16) short z2s[64 * Z_S];        // 16 KiB
    __shared__ __align__(16) short aow_s[4 * 12 * 8];    // out A-frags [ks][mrow<3][q]
    __shared__ __align__(16) float bias_s[4 * 128 + 16]; // h1,g1',h2,g2' + vob'
    __shared__ __align__(8)  unsigned a1_s[2 * 256];     // layer1 A rows (h, g')

    const int tid  = threadIdx.x;
    const int w    = tid >> 6;        // wave id 0..7
    const int lane = tid & 63;
    const int q    = lane >> 4;       // quad 0..3
    const int m    = lane & 15;       // MFMA row (A) / col (B,C)

    // ---------------- weight preload (once per block, reused by TPB tiles) ----
    const int row = 16 * w + m;                 // this lane's A-row (channel)
    bf16x8 a2h[4], a2g[4];                      // layer2 A-frags per k-step (32 regs)
    sfor<0, 4>([&](auto KS) {
        constexpr int ks = KS.value;
        a2h[ks] = pack8s(h2_w + row * 128 + ks * 32 + q * 8, 1.0f);
        a2g[ks] = pack8s(g2_w + row * 128 + ks * 32 + q * 8, -LOG2E);
    });
    // layer1 A rows -> LDS compact (4 bf16 = 8 B per channel, h then g)
    if (tid < 128) {
        const f32x4 t1 = *reinterpret_cast<const f32x4*>(h1_w + tid * 4);
        const f32x4 t2 = *reinterpret_cast<const f32x4*>(g1_w + tid * 4);
        a1_s[tid * 2]           = packbf(t1[0], t1[1]);
        a1_s[tid * 2 + 1]       = packbf(t1[2], t1[3]);
        a1_s[256 + tid * 2]     = packbf(t2[0] * -LOG2E, t2[1] * -LOG2E);
        a1_s[256 + tid * 2 + 1] = packbf(t2[2] * -LOG2E, t2[3] * -LOG2E);
    }
    // out-layer A-frags -> LDS, compact: only real rows m<3 stored
    if (w == 0 && m < 3) {
        sfor<0, 4>([&](auto KS) {
            constexpr int ks = KS.value;
            bf16x8 t = pack8s(out_w + m * 128 + ks * 32 + q * 8, 2.f * LOG2E);
            *reinterpret_cast<bf16x8*>(&aow_s[((ks * 3 + m) * 4 + q) * 8]) = t;
        });
    }
    // biases -> LDS (C-frag reads are wave-broadcast)
    if (tid < 128) {
        bias_s[tid]       = h1_b[tid];
        bias_s[128 + tid] = g1_b[tid] * -LOG2E;
        bias_s[256 + tid] = h2_b[tid];
        bias_s[384 + tid] = g2_b[tid] * -LOG2E;
    }
    if (tid < 16) bias_s[512 + tid] = (tid < 3) ? out_b[tid] * (2.f * LOG2E) : 0.f;

    // zero zin once: shorts 4..7 of each row must stay 0 (A is 0 for k>=4,
    // but 0 * NaN-pattern garbage would poison the MFMA)
    if (tid < 64) *reinterpret_cast<u32x4*>(&zin[tid * 8]) = u32x4{0u, 0u, 0u, 0u};
    __syncthreads();

    const float third = 1.0f / 3.0f;
    const int cb4 = 16 * w + 4 * q;   // this lane's C-frag channel base

    // swizzle helpers: element (row r, 16B-col c) lives at col c ^ (r&7).
    // Row index never changes r&7 across nt (nt*16 rows), so the XOR folds
    // entirely into two base pointers: even-ks and odd-ks.
    const int m7   = m & 7;
    const int qx8  = (q ^ (m & 3)) * 8;     // q-part of swizzled col, shorts
    const int m4_8 = (m & 4) * 8;           // ks-part toggle, shorts

    // hoisted per-lane LDS base pointers (stage/tile-invariant)
    const short* zin_rd = &zin[m * 8];                    // + nt*128 (all lanes; q>0 bcast)
    short*       zin_wr = &zin[row * 8];                  // lanes<16, w<4
    const short* z1_re  = &z1s[m * Z_S + qx8 + m4_8];         // even ks: +nt*2048 +ks*32
    const short* z1_ro  = &z1s[m * Z_S + qx8 + (m4_8 ^ 32)];  // odd ks: +nt*2048 +(ks-1)*32
    short*       z1_wr  = &z1s[m * Z_S + (((2 * w + (q >> 1)) ^ m7) * 8) + (q & 1) * 4];
    short*       z2_wr  = &z2s[m * Z_S + (((2 * w + (q >> 1)) ^ m7) * 8) + (q & 1) * 4];
    const short* z2_re  = &z2s[(16 * w + m) * Z_S + qx8 + m4_8];        // w<4, +ks*32
    const short* z2_ro  = &z2s[(16 * w + m) * Z_S + qx8 + (m4_8 ^ 32)];
    const short* aow_rd = &aow_s[((m < 3 ? m : 2) * 4 + q) * 8];        // + ks*96
    const float* bs     = &bias_s[cb4];                   // +0,+128,+256,+384
    const float* bsov   = &bias_s[512 + 4 * q];

    #pragma unroll 1
    for (int t2 = 0; t2 < TPB; ++t2) {
        const int tile = blockIdx.x * TPB + t2;

        // RK4 state: waves 0-3, lanes 0-15 (point = tile*64 + w*16 + lane)
        float xc0 = 0.f, xc1 = 0.f, xc2 = 0.f;
        int gbase = 0;
        if (w < 4 && lane < 16) {
            const int pg = tile * 64 + w * 16 + lane;
            const int bb = pg / NPT;
            const int nn = pg - bb * NPT;
            gbase = bb * 3 * NPT + nn;
            xc0 = x0[gbase]; xc1 = x0[gbase + NPT]; xc2 = x0[gbase + 2 * NPT];
        }
        float k1x=0,k1y=0,k1z=0, k2x=0,k2y=0,k2z=0, k3x=0,k3y=0,k3z=0;
        float ax=0, ay=0, az=0;

        #pragma unroll 1
        for (int s = 0; s < 4; ++s) {
            // ---- stage input -> zin (B-frag rows; owner lanes only) ----
            if (w < 4 && lane < 16) {
                float zi0, zi1, zi2, tt;
                if (s == 0)      { zi0 = xc0; zi1 = xc1; zi2 = xc2; tt = 0.f; }
                else if (s == 1) { zi0 = fmaf(k1x, third, xc0);
                                   zi1 = fmaf(k1y, third, xc1);
                                   zi2 = fmaf(k1z, third, xc2); tt = third; }
                else if (s == 2) { zi0 = xc0 + (k2x - k1x * third);
                                   zi1 = xc1 + (k2y - k1y * third);
                                   zi2 = xc2 + (k2z - k1z * third); tt = 2.f * third; }
                else             { zi0 = xc0 + (k1x - k2x + k3x);
                                   zi1 = xc1 + (k1y - k2y + k3y);
                                   zi2 = xc2 + (k1z - k2z + k3z); tt = 1.f; }
                u32x2 pk = { packbf(zi0, zi1), packbf(zi2, tt) };
                *reinterpret_cast<u32x2*>(zin_wr) = pk;
            }
            __syncthreads();

            // ---- layer 1 (4->128, K-padded MFMA); A-frags rebuilt from LDS ----
            {
                bf16x8 a1h = {0,0,0,0,0,0,0,0}, a1g = {0,0,0,0,0,0,0,0};
                if (q == 0) {
                    u32x2 th = *reinterpret_cast<const u32x2*>(&a1_s[row * 2]);
                    u32x2 tg = *reinterpret_cast<const u32x2*>(&a1_s[256 + row * 2]);
                    u32x4 uh = { th[0], th[1], 0u, 0u };
                    u32x4 ug = { tg[0], tg[1], 0u, 0u };
                    a1h = __builtin_bit_cast(bf16x8, uh);
                    a1g = __builtin_bit_cast(bf16x8, ug);
                }
                const f32x4 b1h = *reinterpret_cast<const f32x4*>(bs);
                const f32x4 b1g = *reinterpret_cast<const f32x4*>(bs + 128);
                sfor<0, 4>([&](auto NT) {
                    constexpr int nt = NT.value;
                    bf16x8 bf = *reinterpret_cast<const bf16x8*>(zin_rd + nt * 128);
                    f32x4 ch = mfma16(a1h, bf, b1h);
                    f32x4 cg = mfma16(a1g, bf, b1g);
                    u32x2 pk = { gate2p(f32x2{ch[0], ch[1]}, f32x2{cg[0], cg[1]}),
                                 gate2p(f32x2{ch[2], ch[3]}, f32x2{cg[2], cg[3]}) };
                    *reinterpret_cast<u32x2*>(z1_wr + nt * 2048) = pk;
                });
            }
            __syncthreads();

            // ---- layer 2 (128->128); fully unrolled, bias rides in as C ----
            {
                const f32x4 b2h = *reinterpret_cast<const f32x4*>(bs + 256);
                const f32x4 b2g = *reinterpret_cast<const f32x4*>(bs + 384);
                f32x4 ch[4], cg[4];
                sfor<0, 4>([&](auto NT) {
                    constexpr int nt = NT.value;
                    bf16x8 bf = *reinterpret_cast<const bf16x8*>(z1_re + nt * 2048);
                    ch[nt] = mfma16(a2h[0], bf, b2h);
                    cg[nt] = mfma16(a2g[0], bf, b2g);
                });
                sfor<1, 4>([&](auto KS) {
                    constexpr int ks = KS.value;
                    const short* zb = (ks & 1) ? z1_ro : z1_re;
                    constexpr int koff = (ks & 2) ? 64 : 0;
                    sfor<0, 4>([&](auto NT) {
                        constexpr int nt = NT.value;
                        bf16x8 bf = *reinterpret_cast<const bf16x8*>(zb + nt * 2048 + koff);
                        ch[nt] = mfma16(a2h[ks], bf, ch[nt]);
                        cg[nt] = mfma16(a2g[ks], bf, cg[nt]);
                    });
                });
                sfor<0, 4>([&](auto NT) {
                    constexpr int nt = NT.value;
                    u32x2 pk = { gate2p(f32x2{ch[nt][0], ch[nt][1]}, f32x2{cg[nt][0], cg[nt][1]}),
                                 gate2p(f32x2{ch[nt][2], ch[nt][3]}, f32x2{cg[nt][2], cg[nt][3]}) };
                    *reinterpret_cast<u32x2*>(z2_wr + nt * 2048) = pk;
                });
            }
            __syncthreads();

            // ---- out layer (128->3, M padded to 16); waves 0-3, 16 pts each ----
            if (w < 4) {
                f32x4 vc = *reinterpret_cast<const f32x4*>(bsov);
                sfor<0, 4>([&](auto KS) {
                    constexpr int ks = KS.value;
                    bf16x8 af = *reinterpret_cast<const bf16x8*>(aow_rd + ks * 96);
                    const short* zb = (ks & 1) ? z2_ro : z2_re;
                    constexpr int koff = (ks & 2) ? 64 : 0;
                    bf16x8 bf = *reinterpret_cast<const bf16x8*>(zb + koff);
                    vc = mfma16(af, bf, vc);
                });
                // khalf = tanh*0.5 = 0.5 - 1/p, p = 2^v' + 1 (scale folded into
                // out weights). Pair kx,ky through one rcp (packed add); kz single.
                f32x2 e; e.x = fexp2(vc[0]); e.y = fexp2(vc[1]);
                f32x2 p = e + 1.f;
                const float ipxy = frcp(p.x * p.y);
                const float kx = 0.5f - p.y * ipxy;
                const float ky = 0.5f - p.x * ipxy;
                const float kz = 0.5f - frcp(fexp2(vc[2]) + 1.f);

                if (s == 0)      { k1x=kx;k1y=ky;k1z=kz; ax=kx;ay=ky;az=kz; }
                else if (s == 1) { k2x=kx;k2y=ky;k2z=kz;
                                   ax=fmaf(3.f,kx,ax); ay=fmaf(3.f,ky,ay); az=fmaf(3.f,kz,az); }
                else if (s == 2) { k3x=kx;k3y=ky;k3z=kz;
                                   ax=fmaf(3.f,kx,ax); ay=fmaf(3.f,ky,ay); az=fmaf(3.f,kz,az); }
                else             { ax+=kx; ay+=ky; az+=kz; }
            }
        }

        if (w < 4 && lane < 16) {
            y[gbase]           = fmaf(0.125f, ax, xc0);
            y[gbase + NPT]     = fmaf(0.125f, ay, xc1);
            y[gbase + 2 * NPT] = fmaf(0.125f, az, xc2);
        }
        __syncthreads();   // zin/z1/z2 reuse safety across tiles
    }
}

extern "C" void kernel_launch(void* const* d_in, const int* in_sizes, int n_in,
                              void* d_out, int out_size, void* d_ws, size_t ws_size,
                              hipStream_t stream) {
    (void)in_sizes; (void)n_in; (void)d_ws; (void)ws_size; (void)out_size;
    const float* x0    = (const float*)d_in[0];
    const float* h1_w  = (const float*)d_in[1];
    const float* h1_b  = (const float*)d_in[2];
    const float* g1_w  = (const float*)d_in[3];
    const float* g1_b  = (const float*)d_in[4];
    const float* h2_w  = (const float*)d_in[5];
    const float* h2_b  = (const float*)d_in[6];
    const float* g2_w  = (const float*)d_in[7];
    const float* g2_b  = (const float*)d_in[8];
    const float* out_w = (const float*)d_in[9];
    const float* out_b = (const float*)d_in[10];
    float* y = (float*)d_out;

    // two 64-pt tiles per 512-thread block
    node_rk4_mfma<<<NTILES / TPB, 512, 0, stream>>>(
        x0, h1_w, h1_b, g1_w, g1_b, h2_w, h2_b, g2_w, g2_b, out_w, out_b, y);
}

// Round 4
// 279.429 us; speedup vs baseline: 1.9529x; 1.0480x over previous
//
#include <hip/hip_runtime.h>
#include <math.h>
#include <utility>

typedef __attribute__((ext_vector_type(8))) short    bf16x8;
typedef __attribute__((ext_vector_type(4))) float    f32x4;
typedef __attribute__((ext_vector_type(2))) float    f32x2;
typedef __attribute__((ext_vector_type(2))) unsigned u32x2;
typedef __attribute__((ext_vector_type(4))) unsigned u32x4;

template<int I, int N, class F>
__device__ __forceinline__ void sfor(F&& f) {
    if constexpr (I < N) { f(std::integral_constant<int, I>{}); sfor<I + 1, N>(static_cast<F&&>(f)); }
}

#define NPT    50000
#define NBLK   3125     // 400000 pts / 128 per block (two 64-pt tiles, concurrent)
#define Z_S    128      // shorts per z1/z2 row (256 B), XOR-swizzled 16B columns
#define LOG2E  1.4426950408889634f

// dynamic-LDS byte offsets (all 16B-aligned)
#define OFF_Z1   0        // 2 tiles x 64 rows x 128 shorts = 32768 B
#define OFF_Z2   32768    // 32768 B
#define OFF_ZIN  65536    // 2 tiles x 64 rows x 8 shorts   = 2048 B
#define OFF_KST  67584    // 2 tiles x 3 slots x 64 pts x f32x4 = 6144 B
#define OFF_AOW  73728    // 4*12*8 shorts = 768 B
#define OFF_BIAS 74496    // 528 f32 = 2112 B
#define OFF_A1   76608    // 512 u32 = 2048 B
#define LDS_BYTES 78656
#define TBZ   8192   // tile-B offset in z1/z2, shorts
#define TBZIN 512    // tile-B offset in zin, shorts
#define TBK   768    // tile-B offset in kst, floats

static __device__ __forceinline__ unsigned short bf16r(float f) {   // RNE f32->bf16
    unsigned u = __builtin_bit_cast(unsigned, f);
    u += 0x7FFFu + ((u >> 16) & 1u);
    return (unsigned short)(u >> 16);
}

#if defined(__has_builtin)
#if __has_builtin(__builtin_amdgcn_cvt_pk_bf16_f32)
#define HAVE_CVT_PK_BF16 1
#endif
#if __has_builtin(__builtin_amdgcn_exp2f) && __has_builtin(__builtin_amdgcn_rcpf)
#define HAVE_RAW_TRANS 1
#endif
#endif

static __device__ __forceinline__ unsigned packbf(float a, float b) {
#ifdef HAVE_CVT_PK_BF16
    return __builtin_bit_cast(unsigned, __builtin_amdgcn_cvt_pk_bf16_f32(a, b));
#else
    return (unsigned)bf16r(a) | ((unsigned)bf16r(b) << 16);
#endif
}

#ifdef HAVE_RAW_TRANS
static __device__ __forceinline__ float fexp2(float x) { return __builtin_amdgcn_exp2f(x); }
static __device__ __forceinline__ float frcp(float x)  { return __builtin_amdgcn_rcpf(x); }
#else
static __device__ __forceinline__ float fexp2(float x) { return __exp2f(x); }
static __device__ __forceinline__ float frcp(float x)  { return __frcp_rn(x); }
#endif

// paired gated activation, packed-f32 form. g pre-scaled by -log2e so
// sigma_i = 1/(1 + 2^gp_i); one shared v_rcp via reciprocal-product.
static __device__ __forceinline__ unsigned gate2p(f32x2 h, f32x2 gp) {
    f32x2 e;
    e.x = fexp2(gp.x);
    e.y = fexp2(gp.y);
    f32x2 p = e + 1.f;                                   // v_pk_add_f32
    float ip = frcp(p.x * p.y);
    f32x2 ps = __builtin_shufflevector(p, p, 1, 0);      // op_sel swizzle
    f32x2 z = (h * ps) * ip;                             // v_pk_mul_f32 x2
    z = __builtin_elementwise_max(z, f32x2{0.f, 0.f});   // v_pk_max_f32
    return packbf(z.x, z.y);
}

static __device__ __forceinline__ bf16x8 pack8s(const float* p, float s) { // p 16B-aligned
    f32x4 lo = *reinterpret_cast<const f32x4*>(p);
    f32x4 hi = *reinterpret_cast<const f32x4*>(p + 4);
    u32x4 u = { packbf(lo[0]*s, lo[1]*s), packbf(lo[2]*s, lo[3]*s),
                packbf(hi[0]*s, hi[1]*s), packbf(hi[2]*s, hi[3]*s) };
    return __builtin_bit_cast(bf16x8, u);
}
static __device__ __forceinline__ f32x4 mfma16(bf16x8 a, bf16x8 b, f32x4 c) {
    return __builtin_amdgcn_mfma_f32_16x16x32_bf16(a, b, c, 0, 0, 0);
}

// Round-15: dual-tile CONCURRENT schedule. R3 showed occupancy is walled at
// 2 blocks/CU (total regs ~128: arch 64 + acc 64; 3 blocks needs <=85 —
// unreachable past 32 regs of weight frags). So attack barrier-drain count:
// both 64-pt tiles advance through each phase under SHARED barriers ->
// 13 barrier events/block instead of 26, 2x independent work per region.
// Register budget kept <=128 by: k1..k3 state in LDS (same-lane write/read,
// no barrier needed), L2 accumulators split to nt-pairs (live 16 regs).
// LDS 76.8 KB/block (dynamic) -> still 2 blocks/CU.
__global__ __launch_bounds__(512, 4) void node_rk4_mfma(
    const float* __restrict__ x0,
    const float* __restrict__ h1_w, const float* __restrict__ h1_b,
    const float* __restrict__ g1_w, const float* __restrict__ g1_b,
    const float* __restrict__ h2_w, const float* __restrict__ h2_b,
    const float* __restrict__ g2_w, const float* __restrict__ g2_b,
    const float* __restrict__ out_w, const float* __restrict__ out_b,
    float* __restrict__ y)
{
    extern __shared__ char lds_raw[];
    short*    z1s    = reinterpret_cast<short*>(lds_raw + OFF_Z1);
    short*    z2s    = reinterpret_cast<short*>(lds_raw + OFF_Z2);
    short*    zin    = reinterpret_cast<short*>(lds_raw + OFF_ZIN);
    float*    kst    = reinterpret_cast<float*>(lds_raw + OFF_KST);
    short*    aow_s  = reinterpret_cast<short*>(lds_raw + OFF_AOW);
    float*    bias_s = reinterpret_cast<float*>(lds_raw + OFF_BIAS);
    unsigned* a1_s   = reinterpret_cast<unsigned*>(lds_raw + OFF_A1);

    const int tid  = threadIdx.x;
    const int w    = tid >> 6;        // wave id 0..7
    const int lane = tid & 63;
    const int q    = lane >> 4;       // quad 0..3
    const int m    = lane & 15;       // MFMA row (A) / col (B,C)

    // ---------------- weight preload (once per block) ----
    const int row = 16 * w + m;                 // this lane's A-row (channel)
    bf16x8 a2h[4], a2g[4];                      // layer2 A-frags per k-step (32 regs)
    sfor<0, 4>([&](auto KS) {
        constexpr int ks = KS.value;
        a2h[ks] = pack8s(h2_w + row * 128 + ks * 32 + q * 8, 1.0f);
        a2g[ks] = pack8s(g2_w + row * 128 + ks * 32 + q * 8, -LOG2E);
    });
    // layer1 A rows -> LDS compact (4 bf16 = 8 B per channel, h then g)
    if (tid < 128) {
        const f32x4 t1 = *reinterpret_cast<const f32x4*>(h1_w + tid * 4);
        const f32x4 t2 = *reinterpret_cast<const f32x4*>(g1_w + tid * 4);
        a1_s[tid * 2]           = packbf(t1[0], t1[1]);
        a1_s[tid * 2 + 1]       = packbf(t1[2], t1[3]);
        a1_s[256 + tid * 2]     = packbf(t2[0] * -LOG2E, t2[1] * -LOG2E);
        a1_s[256 + tid * 2 + 1] = packbf(t2[2] * -LOG2E, t2[3] * -LOG2E);
    }
    // out-layer A-frags -> LDS, compact: only real rows m<3 stored
    if (w == 0 && m < 3) {
        sfor<0, 4>([&](auto KS) {
            constexpr int ks = KS.value;
            bf16x8 t = pack8s(out_w + m * 128 + ks * 32 + q * 8, 2.f * LOG2E);
            *reinterpret_cast<bf16x8*>(&aow_s[((ks * 3 + m) * 4 + q) * 8]) = t;
        });
    }
    // biases -> LDS
    if (tid < 128) {
        bias_s[tid]       = h1_b[tid];
        bias_s[128 + tid] = g1_b[tid] * -LOG2E;
        bias_s[256 + tid] = h2_b[tid];
        bias_s[384 + tid] = g2_b[tid] * -LOG2E;
    }
    if (tid < 16) bias_s[512 + tid] = (tid < 3) ? out_b[tid] * (2.f * LOG2E) : 0.f;

    // zero zin (both tiles): shorts 4..7 of each row must stay 0
    if (tid < 128) *reinterpret_cast<u32x4*>(&zin[tid * 8]) = u32x4{0u, 0u, 0u, 0u};
    __syncthreads();

    const float third = 1.0f / 3.0f;
    const int cb4 = 16 * w + 4 * q;   // this lane's C-frag channel base

    // swizzle helpers (verified in R13): (row r, 16B-col c) lives at c ^ (r&7)
    const int m7   = m & 7;
    const int qx8  = (q ^ (m & 3)) * 8;     // q-part of swizzled col, shorts
    const int m4_8 = (m & 4) * 8;           // ks-part toggle, shorts

    // hoisted per-lane LDS base pointers (tile-A bases; tile-B = +const)
    const short* zin_rd = &zin[m * 8];
    short*       zin_wr = &zin[row * 8];                  // lanes<16, w<4
    const short* z1_re  = &z1s[m * Z_S + qx8 + m4_8];
    const short* z1_ro  = &z1s[m * Z_S + qx8 + (m4_8 ^ 32)];
    short*       z1_wr  = &z1s[m * Z_S + (((2 * w + (q >> 1)) ^ m7) * 8) + (q & 1) * 4];
    short*       z2_wr  = &z2s[m * Z_S + (((2 * w + (q >> 1)) ^ m7) * 8) + (q & 1) * 4];
    const short* z2_re  = &z2s[(16 * w + m) * Z_S + qx8 + m4_8];        // w<4
    const short* z2_ro  = &z2s[(16 * w + m) * Z_S + qx8 + (m4_8 ^ 32)];
    const short* aow_rd = &aow_s[((m < 3 ? m : 2) * 4 + q) * 8];        // + ks*96
    const float* bs     = &bias_s[cb4];                   // +0,+128,+256,+384
    const float* bsov   = &bias_s[512 + 4 * q];
    float*       kbase  = &kst[row * 4];                  // k-state rows (w<4, lane<16)

    // ---------------- prologue: dual RK4 state ----
    float xcA0=0.f, xcA1=0.f, xcA2=0.f, xcB0=0.f, xcB1=0.f, xcB2=0.f;
    int gbA = 0, gbB = 0;
    if (w < 4 && lane < 16) {
        const int pgA = blockIdx.x * 128 + row;
        const int bbA = pgA / NPT;
        gbA = bbA * 3 * NPT + (pgA - bbA * NPT);
        xcA0 = x0[gbA]; xcA1 = x0[gbA + NPT]; xcA2 = x0[gbA + 2 * NPT];
        const int pgB = pgA + 64;
        const int bbB = pgB / NPT;
        gbB = bbB * 3 * NPT + (pgB - bbB * NPT);
        xcB0 = x0[gbB]; xcB1 = x0[gbB + NPT]; xcB2 = x0[gbB + 2 * NPT];
    }
    float axA=0.f, ayA=0.f, azA=0.f, axB=0.f, ayB=0.f, azB=0.f;

    #pragma unroll 1
    for (int s = 0; s < 4; ++s) {
        // ---- stage inputs -> zin, both tiles (owner lanes only) ----
        if (w < 4 && lane < 16) {
            auto STAGET = [&](auto TT, float x0c, float x1c, float x2c) {
                constexpr int T = TT.value;
                const float* kb = kbase + T * TBK;
                float zi0, zi1, zi2, tt;
                if (s == 0)      { zi0 = x0c; zi1 = x1c; zi2 = x2c; tt = 0.f; }
                else if (s == 1) {
                    f32x4 k1 = *reinterpret_cast<const f32x4*>(kb);
                    zi0 = fmaf(k1[0], third, x0c);
                    zi1 = fmaf(k1[1], third, x1c);
                    zi2 = fmaf(k1[2], third, x2c); tt = third;
                } else if (s == 2) {
                    f32x4 k1 = *reinterpret_cast<const f32x4*>(kb);
                    f32x4 k2 = *reinterpret_cast<const f32x4*>(kb + 256);
                    zi0 = x0c + (k2[0] - k1[0] * third);
                    zi1 = x1c + (k2[1] - k1[1] * third);
                    zi2 = x2c + (k2[2] - k1[2] * third); tt = 2.f * third;
                } else {
                    f32x4 k1 = *reinterpret_cast<const f32x4*>(kb);
                    f32x4 k2 = *reinterpret_cast<const f32x4*>(kb + 256);
                    f32x4 k3 = *reinterpret_cast<const f32x4*>(kb + 512);
                    zi0 = x0c + (k1[0] - k2[0] + k3[0]);
                    zi1 = x1c + (k1[1] - k2[1] + k3[1]);
                    zi2 = x2c + (k1[2] - k2[2] + k3[2]); tt = 1.f;
                }
                u32x2 pk = { packbf(zi0, zi1), packbf(zi2, tt) };
                *reinterpret_cast<u32x2*>(zin_wr + T * TBZIN) = pk;
            };
            STAGET(std::integral_constant<int, 0>{}, xcA0, xcA1, xcA2);
            STAGET(std::integral_constant<int, 1>{}, xcB0, xcB1, xcB2);
        }
        __syncthreads();

        // ---- layer 1 (4->128), both tiles ----
        {
            bf16x8 a1h = {0,0,0,0,0,0,0,0}, a1g = {0,0,0,0,0,0,0,0};
            if (q == 0) {
                u32x2 th = *reinterpret_cast<const u32x2*>(&a1_s[row * 2]);
                u32x2 tg = *reinterpret_cast<const u32x2*>(&a1_s[256 + row * 2]);
                u32x4 uh = { th[0], th[1], 0u, 0u };
                u32x4 ug = { tg[0], tg[1], 0u, 0u };
                a1h = __builtin_bit_cast(bf16x8, uh);
                a1g = __builtin_bit_cast(bf16x8, ug);
            }
            const f32x4 b1h = *reinterpret_cast<const f32x4*>(bs);
            const f32x4 b1g = *reinterpret_cast<const f32x4*>(bs + 128);
            auto L1T = [&](auto TT) {
                constexpr int T = TT.value;
                sfor<0, 4>([&](auto NT) {
                    constexpr int nt = NT.value;
                    bf16x8 bf = *reinterpret_cast<const bf16x8*>(zin_rd + T * TBZIN + nt * 128);
                    f32x4 ch = mfma16(a1h, bf, b1h);
                    f32x4 cg = mfma16(a1g, bf, b1g);
                    u32x2 pk = { gate2p(f32x2{ch[0], ch[1]}, f32x2{cg[0], cg[1]}),
                                 gate2p(f32x2{ch[2], ch[3]}, f32x2{cg[2], cg[3]}) };
                    *reinterpret_cast<u32x2*>(z1_wr + T * TBZ + nt * 2048) = pk;
                });
            };
            L1T(std::integral_constant<int, 0>{});
            L1T(std::integral_constant<int, 1>{});
        }
        __syncthreads();

        // ---- layer 2 (128->128), both tiles; nt-pair split keeps acc at 16 ----
        {
            const f32x4 b2h = *reinterpret_cast<const f32x4*>(bs + 256);
            const f32x4 b2g = *reinterpret_cast<const f32x4*>(bs + 384);
            auto L2T = [&](auto TT) {
                constexpr int T = TT.value;
                sfor<0, 2>([&](auto NTP) {
                    constexpr int b0 = T * TBZ + (2 * NTP.value) * 2048;
                    constexpr int b1 = T * TBZ + (2 * NTP.value + 1) * 2048;
                    f32x4 c0h, c1h, c0g, c1g;
                    {
                        bf16x8 f0 = *reinterpret_cast<const bf16x8*>(z1_re + b0);
                        bf16x8 f1 = *reinterpret_cast<const bf16x8*>(z1_re + b1);
                        c0h = mfma16(a2h[0], f0, b2h); c1h = mfma16(a2h[0], f1, b2h);
                        c0g = mfma16(a2g[0], f0, b2g); c1g = mfma16(a2g[0], f1, b2g);
                    }
                    sfor<1, 4>([&](auto KS) {
                        constexpr int ks = KS.value;
                        const short* zb = (ks & 1) ? z1_ro : z1_re;
                        constexpr int koff = (ks & 2) ? 64 : 0;
                        bf16x8 f0 = *reinterpret_cast<const bf16x8*>(zb + b0 + koff);
                        bf16x8 f1 = *reinterpret_cast<const bf16x8*>(zb + b1 + koff);
                        c0h = mfma16(a2h[ks], f0, c0h); c1h = mfma16(a2h[ks], f1, c1h);
                        c0g = mfma16(a2g[ks], f0, c0g); c1g = mfma16(a2g[ks], f1, c1g);
                    });
                    u32x2 pk0 = { gate2p(f32x2{c0h[0], c0h[1]}, f32x2{c0g[0], c0g[1]}),
                                  gate2p(f32x2{c0h[2], c0h[3]}, f32x2{c0g[2], c0g[3]}) };
                    *reinterpret_cast<u32x2*>(z2_wr + b0) = pk0;
                    u32x2 pk1 = { gate2p(f32x2{c1h[0], c1h[1]}, f32x2{c1g[0], c1g[1]}),
                                  gate2p(f32x2{c1h[2], c1h[3]}, f32x2{c1g[2], c1g[3]}) };
                    *reinterpret_cast<u32x2*>(z2_wr + b1) = pk1;
                });
            };
            L2T(std::integral_constant<int, 0>{});
            L2T(std::integral_constant<int, 1>{});
        }
        __syncthreads();

        // ---- out layer (128->3), both tiles; waves 0-3, 16 pts each ----
        if (w < 4) {
            auto OUTT = [&](auto TT, float& ax, float& ay, float& az) {
                constexpr int T = TT.value;
                f32x4 vc = *reinterpret_cast<const f32x4*>(bsov);
                sfor<0, 4>([&](auto KS) {
                    constexpr int ks = KS.value;
                    bf16x8 af = *reinterpret_cast<const bf16x8*>(aow_rd + ks * 96);
                    const short* zb = (ks & 1) ? z2_ro : z2_re;
                    constexpr int koff = (ks & 2) ? 64 : 0;
                    bf16x8 bf = *reinterpret_cast<const bf16x8*>(zb + T * TBZ + koff);
                    vc = mfma16(af, bf, vc);
                });
                // khalf = tanh*0.5 = 0.5 - 1/p, p = 2^v' + 1 (scale folded into
                // out weights). Pair kx,ky through one rcp; kz single.
                f32x2 e; e.x = fexp2(vc[0]); e.y = fexp2(vc[1]);
                f32x2 p = e + 1.f;
                const float ipxy = frcp(p.x * p.y);
                const float kx = 0.5f - p.y * ipxy;
                const float ky = 0.5f - p.x * ipxy;
                const float kz = 0.5f - frcp(fexp2(vc[2]) + 1.f);
                if (lane < 16 && s < 3)
                    *reinterpret_cast<f32x4*>(kbase + T * TBK + s * 256) = f32x4{kx, ky, kz, 0.f};
                if (s == 0)      { ax = kx; ay = ky; az = kz; }
                else if (s < 3)  { ax = fmaf(3.f, kx, ax); ay = fmaf(3.f, ky, ay); az = fmaf(3.f, kz, az); }
                else             { ax += kx; ay += ky; az += kz; }
            };
            OUTT(std::integral_constant<int, 0>{}, axA, ayA, azA);
            OUTT(std::integral_constant<int, 1>{}, axB, ayB, azB);
        }
    }

    if (w < 4 && lane < 16) {
        y[gbA]           = fmaf(0.125f, axA, xcA0);
        y[gbA + NPT]     = fmaf(0.125f, ayA, xcA1);
        y[gbA + 2 * NPT] = fmaf(0.125f, azA, xcA2);
        y[gbB]           = fmaf(0.125f, axB, xcB0);
        y[gbB + NPT]     = fmaf(0.125f, ayB, xcB1);
        y[gbB + 2 * NPT] = fmaf(0.125f, azB, xcB2);
    }
}

extern "C" void kernel_launch(void* const* d_in, const int* in_sizes, int n_in,
                              void* d_out, int out_size, void* d_ws, size_t ws_size,
                              hipStream_t stream) {
    (void)in_sizes; (void)n_in; (void)d_ws; (void)ws_size; (void)out_size;
    const float* x0    = (const float*)d_in[0];
    const float* h1_w  = (const float*)d_in[1];
    const float* h1_b  = (const float*)d_in[2];
    const float* g1_w  = (const float*)d_in[3];
    const float* g1_b  = (const float*)d_in[4];
    const float* h2_w  = (const float*)d_in[5];
    const float* h2_b  = (const float*)d_in[6];
    const float* g2_w  = (const float*)d_in[7];
    const float* g2_b  = (const float*)d_in[8];
    const float* out_w = (const float*)d_in[9];
    const float* out_b = (const float*)d_in[10];
    float* y = (float*)d_out;

    static bool attr_set = false;
    if (!attr_set) {
        (void)hipFuncSetAttribute(reinterpret_cast<const void*>(&node_rk4_mfma),
                                  hipFuncAttributeMaxDynamicSharedMemorySize, LDS_BYTES);
        attr_set = true;
    }
    node_rk4_mfma<<<NBLK, 512, LDS_BYTES, stream>>>(
        x0, h1_w, h1_b, g1_w, g1_b, h2_w, h2_b, g2_w, g2_b, out_w, out_b, y);
}

// Round 5
// 270.808 us; speedup vs baseline: 2.0151x; 1.0318x over previous
//
#include <hip/hip_runtime.h>
#include <math.h>
#include <utility>

typedef __attribute__((ext_vector_type(8))) short    bf16x8;
typedef __attribute__((ext_vector_type(4))) float    f32x4;
typedef __attribute__((ext_vector_type(2))) float    f32x2;
typedef __attribute__((ext_vector_type(2))) unsigned u32x2;
typedef __attribute__((ext_vector_type(4))) unsigned u32x4;

template<int I, int N, class F>
__device__ __forceinline__ void sfor(F&& f) {
    if constexpr (I < N) { f(std::integral_constant<int, I>{}); sfor<I + 1, N>(static_cast<F&&>(f)); }
}

#define NPT    50000
#define NBLK   3125     // 400000 pts / 128 per block (two 64-pt tiles, concurrent)
#define Z_S    128      // shorts per z1/z2 row (256 B), XOR-swizzled 16B columns
#define LOG2E  1.4426950408889634f

// dynamic-LDS byte offsets (all 16B-aligned)
#define OFF_Z1   0        // 128 rows x 128 shorts = 32768 B (tile A rows 0-63, B 64-127)
#define OFF_Z2   32768    // 32768 B
#define OFF_ZIN  65536    // 128 rows x 8 shorts = 2048 B
#define OFF_KST  67584    // 2 slots x 128 pts x 16 B = 4096 B
#define OFF_AOW  71680    // 4*12*8 shorts = 768 B
#define OFF_BIAS 72448    // 528 f32 = 2112 B
#define OFF_A1   74560    // 512 u32 = 2048 B
#define LDS_BYTES 76608
#define TBZ   8192   // tile-B offset in z1/z2, shorts (64 rows)
#define TBZIN 512    // tile-B offset in zin, shorts (64 rows)

static __device__ __forceinline__ unsigned short bf16r(float f) {   // RNE f32->bf16
    unsigned u = __builtin_bit_cast(unsigned, f);
    u += 0x7FFFu + ((u >> 16) & 1u);
    return (unsigned short)(u >> 16);
}

#if defined(__has_builtin)
#if __has_builtin(__builtin_amdgcn_cvt_pk_bf16_f32)
#define HAVE_CVT_PK_BF16 1
#endif
#if __has_builtin(__builtin_amdgcn_exp2f) && __has_builtin(__builtin_amdgcn_rcpf)
#define HAVE_RAW_TRANS 1
#endif
#endif

static __device__ __forceinline__ unsigned packbf(float a, float b) {
#ifdef HAVE_CVT_PK_BF16
    return __builtin_bit_cast(unsigned, __builtin_amdgcn_cvt_pk_bf16_f32(a, b));
#else
    return (unsigned)bf16r(a) | ((unsigned)bf16r(b) << 16);
#endif
}

#ifdef HAVE_RAW_TRANS
static __device__ __forceinline__ float fexp2(float x) { return __builtin_amdgcn_exp2f(x); }
static __device__ __forceinline__ float frcp(float x)  { return __builtin_amdgcn_rcpf(x); }
#else
static __device__ __forceinline__ float fexp2(float x) { return __exp2f(x); }
static __device__ __forceinline__ float frcp(float x)  { return __frcp_rn(x); }
#endif

// paired gated activation, packed-f32 form. g pre-scaled by -log2e so
// sigma_i = 1/(1 + 2^gp_i); one shared v_rcp via reciprocal-product.
static __device__ __forceinline__ unsigned gate2p(f32x2 h, f32x2 gp) {
    f32x2 e;
    e.x = fexp2(gp.x);
    e.y = fexp2(gp.y);
    f32x2 p = e + 1.f;                                   // v_pk_add_f32
    float ip = frcp(p.x * p.y);
    f32x2 ps = __builtin_shufflevector(p, p, 1, 0);      // op_sel swizzle
    f32x2 z = (h * ps) * ip;                             // v_pk_mul_f32 x2
    z = __builtin_elementwise_max(z, f32x2{0.f, 0.f});   // v_pk_max_f32
    return packbf(z.x, z.y);
}

static __device__ __forceinline__ bf16x8 pack8s(const float* p, float s) { // p 16B-aligned
    f32x4 lo = *reinterpret_cast<const f32x4*>(p);
    f32x4 hi = *reinterpret_cast<const f32x4*>(p + 4);
    u32x4 u = { packbf(lo[0]*s, lo[1]*s), packbf(lo[2]*s, lo[3]*s),
                packbf(hi[0]*s, hi[1]*s), packbf(hi[2]*s, hi[3]*s) };
    return __builtin_bit_cast(bf16x8, u);
}
static __device__ __forceinline__ f32x4 mfma16(bf16x8 a, bf16x8 b, f32x4 c) {
    return __builtin_amdgcn_mfma_f32_16x16x32_bf16(a, b, c, 0, 0, 0);
}

// Round-16: tile-ownership split — no phase idles a wave.
// Uniform point id = 16w+m (0..127): waves 0-3 own tile A's points, waves
// 4-7 own tile B's. Out phase runs on ALL 8 waves (one tile-half each,
// 4 MFMA) instead of waves 0-3 doing both tiles serially; the standalone
// stage phase is DELETED — staging is fused into the out-phase tail (k_s
// in hand; k1/k2 recalled from 2 same-lane LDS slots). L1/L2 unchanged
// (already all-wave x both tiles). Barriers 3/stage (structural minimum:
// three LDS transposes). Register delta vs R4 ~ -6 (single-tile state).
__global__ __launch_bounds__(512, 4) void node_rk4_mfma(
    const float* __restrict__ x0,
    const float* __restrict__ h1_w, const float* __restrict__ h1_b,
    const float* __restrict__ g1_w, const float* __restrict__ g1_b,
    const float* __restrict__ h2_w, const float* __restrict__ h2_b,
    const float* __restrict__ g2_w, const float* __restrict__ g2_b,
    const float* __restrict__ out_w, const float* __restrict__ out_b,
    float* __restrict__ y)
{
    extern __shared__ char lds_raw[];
    short*    z1s    = reinterpret_cast<short*>(lds_raw + OFF_Z1);
    short*    z2s    = reinterpret_cast<short*>(lds_raw + OFF_Z2);
    short*    zin    = reinterpret_cast<short*>(lds_raw + OFF_ZIN);
    float*    kst    = reinterpret_cast<float*>(lds_raw + OFF_KST);
    short*    aow_s  = reinterpret_cast<short*>(lds_raw + OFF_AOW);
    float*    bias_s = reinterpret_cast<float*>(lds_raw + OFF_BIAS);
    unsigned* a1_s   = reinterpret_cast<unsigned*>(lds_raw + OFF_A1);

    const int tid  = threadIdx.x;
    const int w    = tid >> 6;        // wave id 0..7
    const int lane = tid & 63;
    const int q    = lane >> 4;       // quad 0..3
    const int m    = lane & 15;       // MFMA row (A) / col (B,C)

    // ---------------- weight preload (once per block) ----
    const int row = 16 * w + m;                 // lane's A-row (chan) AND point id
    bf16x8 a2h[4], a2g[4];                      // layer2 A-frags per k-step (32 regs)
    sfor<0, 4>([&](auto KS) {
        constexpr int ks = KS.value;
        a2h[ks] = pack8s(h2_w + row * 128 + ks * 32 + q * 8, 1.0f);
        a2g[ks] = pack8s(g2_w + row * 128 + ks * 32 + q * 8, -LOG2E);
    });
    // layer1 A rows -> LDS compact (4 bf16 = 8 B per channel, h then g)
    if (tid < 128) {
        const f32x4 t1 = *reinterpret_cast<const f32x4*>(h1_w + tid * 4);
        const f32x4 t2 = *reinterpret_cast<const f32x4*>(g1_w + tid * 4);
        a1_s[tid * 2]           = packbf(t1[0], t1[1]);
        a1_s[tid * 2 + 1]       = packbf(t1[2], t1[3]);
        a1_s[256 + tid * 2]     = packbf(t2[0] * -LOG2E, t2[1] * -LOG2E);
        a1_s[256 + tid * 2 + 1] = packbf(t2[2] * -LOG2E, t2[3] * -LOG2E);
    }
    // out-layer A-frags -> LDS, compact: only real rows m<3 stored
    if (w == 0 && m < 3) {
        sfor<0, 4>([&](auto KS) {
            constexpr int ks = KS.value;
            bf16x8 t = pack8s(out_w + m * 128 + ks * 32 + q * 8, 2.f * LOG2E);
            *reinterpret_cast<bf16x8*>(&aow_s[((ks * 3 + m) * 4 + q) * 8]) = t;
        });
    }
    // biases -> LDS
    if (tid < 128) {
        bias_s[tid]       = h1_b[tid];
        bias_s[128 + tid] = g1_b[tid] * -LOG2E;
        bias_s[256 + tid] = h2_b[tid];
        bias_s[384 + tid] = g2_b[tid] * -LOG2E;
    }
    if (tid < 16) bias_s[512 + tid] = (tid < 3) ? out_b[tid] * (2.f * LOG2E) : 0.f;

    // zero zin (128 rows): shorts 4..7 of each row must stay 0
    if (tid < 128) *reinterpret_cast<u32x4*>(&zin[tid * 8]) = u32x4{0u, 0u, 0u, 0u};

    const float third = 1.0f / 3.0f;
    const int cb4 = 16 * w + 4 * q;   // this lane's C-frag channel base

    // swizzle helpers (verified R13): (row r, 16B-col c) lives at c ^ (r&7)
    const int m7   = m & 7;
    const int qx8  = (q ^ (m & 3)) * 8;     // q-part of swizzled col, shorts
    const int m4_8 = (m & 4) * 8;           // ks-part toggle, shorts

    // hoisted per-lane LDS base pointers (tile-A bases; tile-B = +const)
    const short* zin_rd = &zin[m * 8];
    short*       zin_wr = &zin[row * 8];                  // lanes<16, all waves
    const short* z1_re  = &z1s[m * Z_S + qx8 + m4_8];
    const short* z1_ro  = &z1s[m * Z_S + qx8 + (m4_8 ^ 32)];
    short*       z1_wr  = &z1s[m * Z_S + (((2 * w + (q >> 1)) ^ m7) * 8) + (q & 1) * 4];
    short*       z2_wr  = &z2s[m * Z_S + (((2 * w + (q >> 1)) ^ m7) * 8) + (q & 1) * 4];
    const short* z2_re  = &z2s[row * Z_S + qx8 + m4_8];       // all waves (rows 0..127)
    const short* z2_ro  = &z2s[row * Z_S + qx8 + (m4_8 ^ 32)];
    const short* aow_rd = &aow_s[((m < 3 ? m : 2) * 4 + q) * 8];        // + ks*96
    const float* bs     = &bias_s[cb4];                   // +0,+128,+256,+384
    const float* bsov   = &bias_s[512 + 4 * q];
    float*       kbase  = &kst[row * 4];                  // k slots (lanes<16); +512/slot

    // ---------------- RK4 state: lanes<16 of every wave own point `row` ----
    float xc0 = 0.f, xc1 = 0.f, xc2 = 0.f;
    int gbase = 0;
    if (lane < 16) {
        const int pg = blockIdx.x * 128 + row;
        const int bb = pg / NPT;
        gbase = bb * 3 * NPT + (pg - bb * NPT);
        xc0 = x0[gbase]; xc1 = x0[gbase + NPT]; xc2 = x0[gbase + 2 * NPT];
    }
    float ax = 0.f, ay = 0.f, az = 0.f;

    // prologue staging: zi = xc, tt = 0
    if (lane < 16) {
        u32x2 pk = { packbf(xc0, xc1), packbf(xc2, 0.f) };
        *reinterpret_cast<u32x2*>(zin_wr) = pk;
    }
    __syncthreads();

    #pragma unroll 1
    for (int s = 0; s < 4; ++s) {
        // ---- layer 1 (4->128), both tiles ----
        {
            bf16x8 a1h = {0,0,0,0,0,0,0,0}, a1g = {0,0,0,0,0,0,0,0};
            if (q == 0) {
                u32x2 th = *reinterpret_cast<const u32x2*>(&a1_s[row * 2]);
                u32x2 tg = *reinterpret_cast<const u32x2*>(&a1_s[256 + row * 2]);
                u32x4 uh = { th[0], th[1], 0u, 0u };
                u32x4 ug = { tg[0], tg[1], 0u, 0u };
                a1h = __builtin_bit_cast(bf16x8, uh);
                a1g = __builtin_bit_cast(bf16x8, ug);
            }
            const f32x4 b1h = *reinterpret_cast<const f32x4*>(bs);
            const f32x4 b1g = *reinterpret_cast<const f32x4*>(bs + 128);
            sfor<0, 2>([&](auto TT) {
                constexpr int T = TT.value;
                sfor<0, 4>([&](auto NT) {
                    constexpr int nt = NT.value;
                    bf16x8 bf = *reinterpret_cast<const bf16x8*>(zin_rd + T * TBZIN + nt * 128);
                    f32x4 ch = mfma16(a1h, bf, b1h);
                    f32x4 cg = mfma16(a1g, bf, b1g);
                    u32x2 pk = { gate2p(f32x2{ch[0], ch[1]}, f32x2{cg[0], cg[1]}),
                                 gate2p(f32x2{ch[2], ch[3]}, f32x2{cg[2], cg[3]}) };
                    *reinterpret_cast<u32x2*>(z1_wr + T * TBZ + nt * 2048) = pk;
                });
            });
        }
        __syncthreads();

        // ---- layer 2 (128->128), both tiles; nt-pair split keeps acc at 16 ----
        {
            const f32x4 b2h = *reinterpret_cast<const f32x4*>(bs + 256);
            const f32x4 b2g = *reinterpret_cast<const f32x4*>(bs + 384);
            sfor<0, 2>([&](auto TT) {
                constexpr int T = TT.value;
                sfor<0, 2>([&](auto NTP) {
                    constexpr int b0 = T * TBZ + (2 * NTP.value) * 2048;
                    constexpr int b1 = T * TBZ + (2 * NTP.value + 1) * 2048;
                    f32x4 c0h, c1h, c0g, c1g;
                    {
                        bf16x8 f0 = *reinterpret_cast<const bf16x8*>(z1_re + b0);
                        bf16x8 f1 = *reinterpret_cast<const bf16x8*>(z1_re + b1);
                        c0h = mfma16(a2h[0], f0, b2h); c1h = mfma16(a2h[0], f1, b2h);
                        c0g = mfma16(a2g[0], f0, b2g); c1g = mfma16(a2g[0], f1, b2g);
                    }
                    sfor<1, 4>([&](auto KS) {
                        constexpr int ks = KS.value;
                        const short* zb = (ks & 1) ? z1_ro : z1_re;
                        constexpr int koff = (ks & 2) ? 64 : 0;
                        bf16x8 f0 = *reinterpret_cast<const bf16x8*>(zb + b0 + koff);
                        bf16x8 f1 = *reinterpret_cast<const bf16x8*>(zb + b1 + koff);
                        c0h = mfma16(a2h[ks], f0, c0h); c1h = mfma16(a2h[ks], f1, c1h);
                        c0g = mfma16(a2g[ks], f0, c0g); c1g = mfma16(a2g[ks], f1, c1g);
                    });
                    u32x2 pk0 = { gate2p(f32x2{c0h[0], c0h[1]}, f32x2{c0g[0], c0g[1]}),
                                  gate2p(f32x2{c0h[2], c0h[3]}, f32x2{c0g[2], c0g[3]}) };
                    *reinterpret_cast<u32x2*>(z2_wr + b0) = pk0;
                    u32x2 pk1 = { gate2p(f32x2{c1h[0], c1h[1]}, f32x2{c1g[0], c1g[1]}),
                                  gate2p(f32x2{c1h[2], c1h[3]}, f32x2{c1g[2], c1g[3]}) };
                    *reinterpret_cast<u32x2*>(z2_wr + b1) = pk1;
                });
            });
        }
        __syncthreads();

        // ---- out layer (128->3) + FUSED staging; all 8 waves, own 16 pts ----
        {
            f32x4 vc = *reinterpret_cast<const f32x4*>(bsov);
            sfor<0, 4>([&](auto KS) {
                constexpr int ks = KS.value;
                bf16x8 af = *reinterpret_cast<const bf16x8*>(aow_rd + ks * 96);
                const short* zb = (ks & 1) ? z2_ro : z2_re;
                constexpr int koff = (ks & 2) ? 64 : 0;
                bf16x8 bf = *reinterpret_cast<const bf16x8*>(zb + koff);
                vc = mfma16(af, bf, vc);
            });
            // khalf = tanh*0.5 = 0.5 - 1/p, p = 2^v' + 1 (scale folded into
            // out weights). Pair kx,ky through one rcp; kz single.
            f32x2 e; e.x = fexp2(vc[0]); e.y = fexp2(vc[1]);
            f32x2 p = e + 1.f;
            const float ipxy = frcp(p.x * p.y);
            const float kx = 0.5f - p.y * ipxy;
            const float ky = 0.5f - p.x * ipxy;
            const float kz = 0.5f - frcp(fexp2(vc[2]) + 1.f);

            if (lane < 16) {
                float zi0, zi1, zi2, tt;
                bool do_stage = true;
                if (s == 0) {
                    ax = kx; ay = ky; az = kz;
                    *reinterpret_cast<f32x4*>(kbase) = f32x4{kx, ky, kz, 0.f};
                    zi0 = fmaf(kx, third, xc0);
                    zi1 = fmaf(ky, third, xc1);
                    zi2 = fmaf(kz, third, xc2); tt = third;
                } else if (s == 1) {
                    ax = fmaf(3.f, kx, ax); ay = fmaf(3.f, ky, ay); az = fmaf(3.f, kz, az);
                    f32x4 k1 = *reinterpret_cast<const f32x4*>(kbase);
                    *reinterpret_cast<f32x4*>(kbase + 512) = f32x4{kx, ky, kz, 0.f};
                    zi0 = xc0 + (kx - k1[0] * third);
                    zi1 = xc1 + (ky - k1[1] * third);
                    zi2 = xc2 + (kz - k1[2] * third); tt = 2.f * third;
                } else if (s == 2) {
                    ax = fmaf(3.f, kx, ax); ay = fmaf(3.f, ky, ay); az = fmaf(3.f, kz, az);
                    f32x4 k1 = *reinterpret_cast<const f32x4*>(kbase);
                    f32x4 k2 = *reinterpret_cast<const f32x4*>(kbase + 512);
                    zi0 = xc0 + (k1[0] - k2[0] + kx);
                    zi1 = xc1 + (k1[1] - k2[1] + ky);
                    zi2 = xc2 + (k1[2] - k2[2] + kz); tt = 1.f;
                } else {
                    ax += kx; ay += ky; az += kz;
                    do_stage = false; zi0 = zi1 = zi2 = tt = 0.f;
                }
                if (do_stage) {
                    u32x2 pk = { packbf(zi0, zi1), packbf(zi2, tt) };
                    *reinterpret_cast<u32x2*>(zin_wr) = pk;
                }
            }
        }
        if (s < 3) __syncthreads();
    }

    if (lane < 16) {
        y[gbase]           = fmaf(0.125f, ax, xc0);
        y[gbase + NPT]     = fmaf(0.125f, ay, xc1);
        y[gbase + 2 * NPT] = fmaf(0.125f, az, xc2);
    }
}

extern "C" void kernel_launch(void* const* d_in, const int* in_sizes, int n_in,
                              void* d_out, int out_size, void* d_ws, size_t ws_size,
                              hipStream_t stream) {
    (void)in_sizes; (void)n_in; (void)d_ws; (void)ws_size; (void)out_size;
    const float* x0    = (const float*)d_in[0];
    const float* h1_w  = (const float*)d_in[1];
    const float* h1_b  = (const float*)d_in[2];
    const float* g1_w  = (const float*)d_in[3];
    const float* g1_b  = (const float*)d_in[4];
    const float* h2_w  = (const float*)d_in[5];
    const float* h2_b  = (const float*)d_in[6];
    const float* g2_w  = (const float*)d_in[7];
    const float* g2_b  = (const float*)d_in[8];
    const float* out_w = (const float*)d_in[9];
    const float* out_b = (const float*)d_in[10];
    float* y = (float*)d_out;

    static bool attr_set = false;
    if (!attr_set) {
        (void)hipFuncSetAttribute(reinterpret_cast<const void*>(&node_rk4_mfma),
                                  hipFuncAttributeMaxDynamicSharedMemorySize, LDS_BYTES);
        attr_set = true;
    }
    node_rk4_mfma<<<NBLK, 512, LDS_BYTES, stream>>>(
        x0, h1_w, h1_b, g1_w, g1_b, h2_w, h2_b, g2_w, g2_b, out_w, out_b, y);
}

// Round 6
// 246.128 us; speedup vs baseline: 2.2171x; 1.1003x over previous
//
#include <hip/hip_runtime.h>
#include <math.h>
#include <utility>

typedef __attribute__((ext_vector_type(8))) short    bf16x8;
typedef __attribute__((ext_vector_type(4))) float    f32x4;
typedef __attribute__((ext_vector_type(2))) float    f32x2;
typedef __attribute__((ext_vector_type(2))) unsigned u32x2;
typedef __attribute__((ext_vector_type(4))) unsigned u32x4;

template<int I, int N, class F>
__device__ __forceinline__ void sfor(F&& f) {
    if constexpr (I < N) { f(std::integral_constant<int, I>{}); sfor<I + 1, N>(static_cast<F&&>(f)); }
}

#define NPT    50000
#define NBLK   3125     // 400000 pts / 128 per block (two 64-pt tiles, concurrent)
#define Z_S    128      // shorts per z1/z2 row (256 B), XOR-swizzled 16B columns
#define LOG2E  1.4426950408889634f

// dynamic-LDS byte offsets (all 16B-aligned)
#define OFF_Z1   0        // 128 rows x 128 shorts = 32768 B (tile A rows 0-63, B 64-127)
#define OFF_Z2   32768    // 32768 B
#define OFF_ZIN  65536    // 128 rows x 8 shorts = 2048 B
#define OFF_KST  67584    // 2 slots x 128 pts x 16 B = 4096 B
#define OFF_AOW  71680    // 4*12*8 shorts = 768 B
#define OFF_BIAS 72448    // 528 f32 = 2112 B
#define OFF_A1   74560    // 512 u32 = 2048 B
#define LDS_BYTES 76608
#define TBZ   8192   // tile-B offset in z1/z2, shorts (64 rows)
#define TBZIN 512    // tile-B offset in zin, shorts (64 rows)

// Round-17: packbf -> HW v_cvt_pk_bf16_f32 via inline asm.
// R5 post-mortem: __builtin_amdgcn_cvt_pk_bf16_f32 does NOT exist on gfx950
// (learn_hip m240), so HAVE_CVT_PK_BF16 was never defined and every packbf
// compiled the ~10-op software RNE fallback. ~34 packbf/wave/stage -> ~300
// hidden VALU instrs/wave/stage — the 2.5x gap between hand-counted VALU
// (~24% busy) and measured (61%). The HW instr does RNE pack in 1 op.
static __device__ __forceinline__ unsigned packbf(float a, float b) {
    unsigned r;
    asm("v_cvt_pk_bf16_f32 %0, %1, %2" : "=v"(r) : "v"(a), "v"(b));
    return r;   // lo16 = bf16(a), hi16 = bf16(b)
}

#if defined(__has_builtin)
#if __has_builtin(__builtin_amdgcn_exp2f) && __has_builtin(__builtin_amdgcn_rcpf)
#define HAVE_RAW_TRANS 1
#endif
#endif

#ifdef HAVE_RAW_TRANS
static __device__ __forceinline__ float fexp2(float x) { return __builtin_amdgcn_exp2f(x); }
static __device__ __forceinline__ float frcp(float x)  { return __builtin_amdgcn_rcpf(x); }
#else
static __device__ __forceinline__ float fexp2(float x) { return __exp2f(x); }
static __device__ __forceinline__ float frcp(float x)  { return __frcp_rn(x); }
#endif

// paired gated activation, packed-f32 form. g pre-scaled by -log2e so
// sigma_i = 1/(1 + 2^gp_i); one shared v_rcp via reciprocal-product.
static __device__ __forceinline__ unsigned gate2p(f32x2 h, f32x2 gp) {
    f32x2 e;
    e.x = fexp2(gp.x);
    e.y = fexp2(gp.y);
    f32x2 p = e + 1.f;                                   // v_pk_add_f32
    float ip = frcp(p.x * p.y);
    f32x2 ps = __builtin_shufflevector(p, p, 1, 0);      // op_sel swizzle
    f32x2 z = (h * ps) * ip;                             // v_pk_mul_f32 x2
    z = __builtin_elementwise_max(z, f32x2{0.f, 0.f});   // v_pk_max_f32
    return packbf(z.x, z.y);
}

static __device__ __forceinline__ bf16x8 pack8s(const float* p, float s) { // p 16B-aligned
    f32x4 lo = *reinterpret_cast<const f32x4*>(p);
    f32x4 hi = *reinterpret_cast<const f32x4*>(p + 4);
    u32x4 u = { packbf(lo[0]*s, lo[1]*s), packbf(lo[2]*s, lo[3]*s),
                packbf(hi[0]*s, hi[1]*s), packbf(hi[2]*s, hi[3]*s) };
    return __builtin_bit_cast(bf16x8, u);
}
static __device__ __forceinline__ f32x4 mfma16(bf16x8 a, bf16x8 b, f32x4 c) {
    return __builtin_amdgcn_mfma_f32_16x16x32_bf16(a, b, c, 0, 0, 0);
}

// Structure (R16): uniform point id = 16w+m; all 8 waves active in every
// phase; staging fused into out-phase tail; k1/k2 recalled from same-lane
// LDS slots; 3 barriers/stage (structural minimum: three LDS transposes).
__global__ __launch_bounds__(512, 4) void node_rk4_mfma(
    const float* __restrict__ x0,
    const float* __restrict__ h1_w, const float* __restrict__ h1_b,
    const float* __restrict__ g1_w, const float* __restrict__ g1_b,
    const float* __restrict__ h2_w, const float* __restrict__ h2_b,
    const float* __restrict__ g2_w, const float* __restrict__ g2_b,
    const float* __restrict__ out_w, const float* __restrict__ out_b,
    float* __restrict__ y)
{
    extern __shared__ char lds_raw[];
    short*    z1s    = reinterpret_cast<short*>(lds_raw + OFF_Z1);
    short*    z2s    = reinterpret_cast<short*>(lds_raw + OFF_Z2);
    short*    zin    = reinterpret_cast<short*>(lds_raw + OFF_ZIN);
    float*    kst    = reinterpret_cast<float*>(lds_raw + OFF_KST);
    short*    aow_s  = reinterpret_cast<short*>(lds_raw + OFF_AOW);
    float*    bias_s = reinterpret_cast<float*>(lds_raw + OFF_BIAS);
    unsigned* a1_s   = reinterpret_cast<unsigned*>(lds_raw + OFF_A1);

    const int tid  = threadIdx.x;
    const int w    = tid >> 6;        // wave id 0..7
    const int lane = tid & 63;
    const int q    = lane >> 4;       // quad 0..3
    const int m    = lane & 15;       // MFMA row (A) / col (B,C)

    // ---------------- weight preload (once per block) ----
    const int row = 16 * w + m;                 // lane's A-row (chan) AND point id
    bf16x8 a2h[4], a2g[4];                      // layer2 A-frags per k-step (32 regs)
    sfor<0, 4>([&](auto KS) {
        constexpr int ks = KS.value;
        a2h[ks] = pack8s(h2_w + row * 128 + ks * 32 + q * 8, 1.0f);
        a2g[ks] = pack8s(g2_w + row * 128 + ks * 32 + q * 8, -LOG2E);
    });
    // layer1 A rows -> LDS compact (4 bf16 = 8 B per channel, h then g)
    if (tid < 128) {
        const f32x4 t1 = *reinterpret_cast<const f32x4*>(h1_w + tid * 4);
        const f32x4 t2 = *reinterpret_cast<const f32x4*>(g1_w + tid * 4);
        a1_s[tid * 2]           = packbf(t1[0], t1[1]);
        a1_s[tid * 2 + 1]       = packbf(t1[2], t1[3]);
        a1_s[256 + tid * 2]     = packbf(t2[0] * -LOG2E, t2[1] * -LOG2E);
        a1_s[256 + tid * 2 + 1] = packbf(t2[2] * -LOG2E, t2[3] * -LOG2E);
    }
    // out-layer A-frags -> LDS, compact: only real rows m<3 stored
    if (w == 0 && m < 3) {
        sfor<0, 4>([&](auto KS) {
            constexpr int ks = KS.value;
            bf16x8 t = pack8s(out_w + m * 128 + ks * 32 + q * 8, 2.f * LOG2E);
            *reinterpret_cast<bf16x8*>(&aow_s[((ks * 3 + m) * 4 + q) * 8]) = t;
        });
    }
    // biases -> LDS
    if (tid < 128) {
        bias_s[tid]       = h1_b[tid];
        bias_s[128 + tid] = g1_b[tid] * -LOG2E;
        bias_s[256 + tid] = h2_b[tid];
        bias_s[384 + tid] = g2_b[tid] * -LOG2E;
    }
    if (tid < 16) bias_s[512 + tid] = (tid < 3) ? out_b[tid] * (2.f * LOG2E) : 0.f;

    // zero zin (128 rows): shorts 4..7 of each row must stay 0
    if (tid < 128) *reinterpret_cast<u32x4*>(&zin[tid * 8]) = u32x4{0u, 0u, 0u, 0u};

    const float third = 1.0f / 3.0f;
    const int cb4 = 16 * w + 4 * q;   // this lane's C-frag channel base

    // swizzle helpers (verified R13): (row r, 16B-col c) lives at c ^ (r&7)
    const int m7   = m & 7;
    const int qx8  = (q ^ (m & 3)) * 8;     // q-part of swizzled col, shorts
    const int m4_8 = (m & 4) * 8;           // ks-part toggle, shorts

    // hoisted per-lane LDS base pointers (tile-A bases; tile-B = +const)
    const short* zin_rd = &zin[m * 8];
    short*       zin_wr = &zin[row * 8];                  // lanes<16, all waves
    const short* z1_re  = &z1s[m * Z_S + qx8 + m4_8];
    const short* z1_ro  = &z1s[m * Z_S + qx8 + (m4_8 ^ 32)];
    short*       z1_wr  = &z1s[m * Z_S + (((2 * w + (q >> 1)) ^ m7) * 8) + (q & 1) * 4];
    short*       z2_wr  = &z2s[m * Z_S + (((2 * w + (q >> 1)) ^ m7) * 8) + (q & 1) * 4];
    const short* z2_re  = &z2s[row * Z_S + qx8 + m4_8];       // all waves (rows 0..127)
    const short* z2_ro  = &z2s[row * Z_S + qx8 + (m4_8 ^ 32)];
    const short* aow_rd = &aow_s[((m < 3 ? m : 2) * 4 + q) * 8];        // + ks*96
    const float* bs     = &bias_s[cb4];                   // +0,+128,+256,+384
    const float* bsov   = &bias_s[512 + 4 * q];
    float*       kbase  = &kst[row * 4];                  // k slots (lanes<16); +512/slot

    // ---------------- RK4 state: lanes<16 of every wave own point `row` ----
    float xc0 = 0.f, xc1 = 0.f, xc2 = 0.f;
    int gbase = 0;
    if (lane < 16) {
        const int pg = blockIdx.x * 128 + row;
        const int bb = pg / NPT;
        gbase = bb * 3 * NPT + (pg - bb * NPT);
        xc0 = x0[gbase]; xc1 = x0[gbase + NPT]; xc2 = x0[gbase + 2 * NPT];
    }
    float ax = 0.f, ay = 0.f, az = 0.f;

    // prologue staging: zi = xc, tt = 0
    if (lane < 16) {
        u32x2 pk = { packbf(xc0, xc1), packbf(xc2, 0.f) };
        *reinterpret_cast<u32x2*>(zin_wr) = pk;
    }
    __syncthreads();

    #pragma unroll 1
    for (int s = 0; s < 4; ++s) {
        // ---- layer 1 (4->128), both tiles ----
        {
            bf16x8 a1h = {0,0,0,0,0,0,0,0}, a1g = {0,0,0,0,0,0,0,0};
            if (q == 0) {
                u32x2 th = *reinterpret_cast<const u32x2*>(&a1_s[row * 2]);
                u32x2 tg = *reinterpret_cast<const u32x2*>(&a1_s[256 + row * 2]);
                u32x4 uh = { th[0], th[1], 0u, 0u };
                u32x4 ug = { tg[0], tg[1], 0u, 0u };
                a1h = __builtin_bit_cast(bf16x8, uh);
                a1g = __builtin_bit_cast(bf16x8, ug);
            }
            const f32x4 b1h = *reinterpret_cast<const f32x4*>(bs);
            const f32x4 b1g = *reinterpret_cast<const f32x4*>(bs + 128);
            sfor<0, 2>([&](auto TT) {
                constexpr int T = TT.value;
                sfor<0, 4>([&](auto NT) {
                    constexpr int nt = NT.value;
                    bf16x8 bf = *reinterpret_cast<const bf16x8*>(zin_rd + T * TBZIN + nt * 128);
                    f32x4 ch = mfma16(a1h, bf, b1h);
                    f32x4 cg = mfma16(a1g, bf, b1g);
                    u32x2 pk = { gate2p(f32x2{ch[0], ch[1]}, f32x2{cg[0], cg[1]}),
                                 gate2p(f32x2{ch[2], ch[3]}, f32x2{cg[2], cg[3]}) };
                    *reinterpret_cast<u32x2*>(z1_wr + T * TBZ + nt * 2048) = pk;
                });
            });
        }
        __syncthreads();

        // ---- layer 2 (128->128), both tiles; nt-pair split keeps acc at 16 ----
        {
            const f32x4 b2h = *reinterpret_cast<const f32x4*>(bs + 256);
            const f32x4 b2g = *reinterpret_cast<const f32x4*>(bs + 384);
            sfor<0, 2>([&](auto TT) {
                constexpr int T = TT.value;
                sfor<0, 2>([&](auto NTP) {
                    constexpr int b0 = T * TBZ + (2 * NTP.value) * 2048;
                    constexpr int b1 = T * TBZ + (2 * NTP.value + 1) * 2048;
                    f32x4 c0h, c1h, c0g, c1g;
                    {
                        bf16x8 f0 = *reinterpret_cast<const bf16x8*>(z1_re + b0);
                        bf16x8 f1 = *reinterpret_cast<const bf16x8*>(z1_re + b1);
                        c0h = mfma16(a2h[0], f0, b2h); c1h = mfma16(a2h[0], f1, b2h);
                        c0g = mfma16(a2g[0], f0, b2g); c1g = mfma16(a2g[0], f1, b2g);
                    }
                    sfor<1, 4>([&](auto KS) {
                        constexpr int ks = KS.value;
                        const short* zb = (ks & 1) ? z1_ro : z1_re;
                        constexpr int koff = (ks & 2) ? 64 : 0;
                        bf16x8 f0 = *reinterpret_cast<const bf16x8*>(zb + b0 + koff);
                        bf16x8 f1 = *reinterpret_cast<const bf16x8*>(zb + b1 + koff);
                        c0h = mfma16(a2h[ks], f0, c0h); c1h = mfma16(a2h[ks], f1, c1h);
                        c0g = mfma16(a2g[ks], f0, c0g); c1g = mfma16(a2g[ks], f1, c1g);
                    });
                    u32x2 pk0 = { gate2p(f32x2{c0h[0], c0h[1]}, f32x2{c0g[0], c0g[1]}),
                                  gate2p(f32x2{c0h[2], c0h[3]}, f32x2{c0g[2], c0g[3]}) };
                    *reinterpret_cast<u32x2*>(z2_wr + b0) = pk0;
                    u32x2 pk1 = { gate2p(f32x2{c1h[0], c1h[1]}, f32x2{c1g[0], c1g[1]}),
                                  gate2p(f32x2{c1h[2], c1h[3]}, f32x2{c1g[2], c1g[3]}) };
                    *reinterpret_cast<u32x2*>(z2_wr + b1) = pk1;
                });
            });
        }
        __syncthreads();

        // ---- out layer (128->3) + FUSED staging; all 8 waves, own 16 pts ----
        {
            f32x4 vc = *reinterpret_cast<const f32x4*>(bsov);
            sfor<0, 4>([&](auto KS) {
                constexpr int ks = KS.value;
                bf16x8 af = *reinterpret_cast<const bf16x8*>(aow_rd + ks * 96);
                const short* zb = (ks & 1) ? z2_ro : z2_re;
                constexpr int koff = (ks & 2) ? 64 : 0;
                bf16x8 bf = *reinterpret_cast<const bf16x8*>(zb + koff);
                vc = mfma16(af, bf, vc);
            });
            // khalf = tanh*0.5 = 0.5 - 1/p, p = 2^v' + 1 (scale folded into
            // out weights). Pair kx,ky through one rcp; kz single.
            f32x2 e; e.x = fexp2(vc[0]); e.y = fexp2(vc[1]);
            f32x2 p = e + 1.f;
            const float ipxy = frcp(p.x * p.y);
            const float kx = 0.5f - p.y * ipxy;
            const float ky = 0.5f - p.x * ipxy;
            const float kz = 0.5f - frcp(fexp2(vc[2]) + 1.f);

            if (lane < 16) {
                float zi0, zi1, zi2, tt;
                bool do_stage = true;
                if (s == 0) {
                    ax = kx; ay = ky; az = kz;
                    *reinterpret_cast<f32x4*>(kbase) = f32x4{kx, ky, kz, 0.f};
                    zi0 = fmaf(kx, third, xc0);
                    zi1 = fmaf(ky, third, xc1);
                    zi2 = fmaf(kz, third, xc2); tt = third;
                } else if (s == 1) {
                    ax = fmaf(3.f, kx, ax); ay = fmaf(3.f, ky, ay); az = fmaf(3.f, kz, az);
                    f32x4 k1 = *reinterpret_cast<const f32x4*>(kbase);
                    *reinterpret_cast<f32x4*>(kbase + 512) = f32x4{kx, ky, kz, 0.f};
                    zi0 = xc0 + (kx - k1[0] * third);
                    zi1 = xc1 + (ky - k1[1] * third);
                    zi2 = xc2 + (kz - k1[2] * third); tt = 2.f * third;
                } else if (s == 2) {
                    ax = fmaf(3.f, kx, ax); ay = fmaf(3.f, ky, ay); az = fmaf(3.f, kz, az);
                    f32x4 k1 = *reinterpret_cast<const f32x4*>(kbase);
                    f32x4 k2 = *reinterpret_cast<const f32x4*>(kbase + 512);
                    zi0 = xc0 + (k1[0] - k2[0] + kx);
                    zi1 = xc1 + (k1[1] - k2[1] + ky);
                    zi2 = xc2 + (k1[2] - k2[2] + kz); tt = 1.f;
                } else {
                    ax += kx; ay += ky; az += kz;
                    do_stage = false; zi0 = zi1 = zi2 = tt = 0.f;
                }
                if (do_stage) {
                    u32x2 pk = { packbf(zi0, zi1), packbf(zi2, tt) };
                    *reinterpret_cast<u32x2*>(zin_wr) = pk;
                }
            }
        }
        if (s < 3) __syncthreads();
    }

    if (lane < 16) {
        y[gbase]           = fmaf(0.125f, ax, xc0);
        y[gbase + NPT]     = fmaf(0.125f, ay, xc1);
        y[gbase + 2 * NPT] = fmaf(0.125f, az, xc2);
    }
}

extern "C" void kernel_launch(void* const* d_in, const int* in_sizes, int n_in,
                              void* d_out, int out_size, void* d_ws, size_t ws_size,
                              hipStream_t stream) {
    (void)in_sizes; (void)n_in; (void)d_ws; (void)ws_size; (void)out_size;
    const float* x0    = (const float*)d_in[0];
    const float* h1_w  = (const float*)d_in[1];
    const float* h1_b  = (const float*)d_in[2];
    const float* g1_w  = (const float*)d_in[3];
    const float* g1_b  = (const float*)d_in[4];
    const float* h2_w  = (const float*)d_in[5];
    const float* h2_b  = (const float*)d_in[6];
    const float* g2_w  = (const float*)d_in[7];
    const float* g2_b  = (const float*)d_in[8];
    const float* out_w = (const float*)d_in[9];
    const float* out_b = (const float*)d_in[10];
    float* y = (float*)d_out;

    static bool attr_set = false;
    if (!attr_set) {
        (void)hipFuncSetAttribute(reinterpret_cast<const void*>(&node_rk4_mfma),
                                  hipFuncAttributeMaxDynamicSharedMemorySize, LDS_BYTES);
        attr_set = true;
    }
    node_rk4_mfma<<<NBLK, 512, LDS_BYTES, stream>>>(
        x0, h1_w, h1_b, g1_w, g1_b, h2_w, h2_b, g2_w, g2_b, out_w, out_b, y);
}

// Round 7
// 241.792 us; speedup vs baseline: 2.2569x; 1.0179x over previous
//
#include <hip/hip_runtime.h>
#include <math.h>
#include <utility>

typedef __attribute__((ext_vector_type(8))) short    bf16x8;
typedef __attribute__((ext_vector_type(4))) float    f32x4;
typedef __attribute__((ext_vector_type(2))) float    f32x2;
typedef __attribute__((ext_vector_type(2))) unsigned u32x2;
typedef __attribute__((ext_vector_type(4))) unsigned u32x4;

template<int I, int N, class F>
__device__ __forceinline__ void sfor(F&& f) {
    if constexpr (I < N) { f(std::integral_constant<int, I>{}); sfor<I + 1, N>(static_cast<F&&>(f)); }
}

#define NPT    50000
#define NBLK   3125     // 400000 pts / 128 per block (two 64-pt tiles, concurrent)
#define Z_S    128      // shorts per z1/z2 row (256 B), XOR-swizzled 16B columns
#define LOG2E  1.4426950408889634f

// dynamic-LDS byte offsets (all 16B-aligned)
#define OFF_Z1   0        // 128 rows x 128 shorts = 32768 B (tile A rows 0-63, B 64-127)
#define OFF_Z2   32768    // 32768 B
#define OFF_ZIN  65536    // 128 rows x 8 shorts = 2048 B
#define OFF_AOW  67584    // 4*12*8 shorts = 768 B
#define OFF_BIAS 68352    // 528 f32 = 2112 B
#define OFF_A1   70464    // 512 u32 = 2048 B
#define LDS_BYTES 72512
#define TBZ   8192   // tile-B offset in z1/z2, shorts (64 rows)
#define TBZIN 512    // tile-B offset in zin, shorts (64 rows)

// packbf: HW v_cvt_pk_bf16_f32 (R17 win: no builtin on gfx950, inline asm
// required; the SW fallback was ~10 VALU ops and 30% of the VALU pipe).
static __device__ __forceinline__ unsigned packbf(float a, float b) {
    unsigned r;
    asm("v_cvt_pk_bf16_f32 %0, %1, %2" : "=v"(r) : "v"(a), "v"(b));
    return r;   // lo16 = bf16(a), hi16 = bf16(b)
}

#if defined(__has_builtin)
#if __has_builtin(__builtin_amdgcn_exp2f) && __has_builtin(__builtin_amdgcn_rcpf)
#define HAVE_RAW_TRANS 1
#endif
#endif

#ifdef HAVE_RAW_TRANS
static __device__ __forceinline__ float fexp2(float x) { return __builtin_amdgcn_exp2f(x); }
static __device__ __forceinline__ float frcp(float x)  { return __builtin_amdgcn_rcpf(x); }
#else
static __device__ __forceinline__ float fexp2(float x) { return __exp2f(x); }
static __device__ __forceinline__ float frcp(float x)  { return __frcp_rn(x); }
#endif

// paired gated activation, packed-f32 form. g pre-scaled by -log2e so
// sigma_i = 1/(1 + 2^gp_i); one shared v_rcp via reciprocal-product.
static __device__ __forceinline__ unsigned gate2p(f32x2 h, f32x2 gp) {
    f32x2 e;
    e.x = fexp2(gp.x);
    e.y = fexp2(gp.y);
    f32x2 p = e + 1.f;                                   // v_pk_add_f32
    float ip = frcp(p.x * p.y);
    f32x2 ps = __builtin_shufflevector(p, p, 1, 0);      // op_sel swizzle
    f32x2 z = (h * ps) * ip;                             // v_pk_mul_f32 x2
    z = __builtin_elementwise_max(z, f32x2{0.f, 0.f});   // v_pk_max_f32
    return packbf(z.x, z.y);
}

static __device__ __forceinline__ bf16x8 pack8s(const float* p, float s) { // p 16B-aligned
    f32x4 lo = *reinterpret_cast<const f32x4*>(p);
    f32x4 hi = *reinterpret_cast<const f32x4*>(p + 4);
    u32x4 u = { packbf(lo[0]*s, lo[1]*s), packbf(lo[2]*s, lo[3]*s),
                packbf(hi[0]*s, hi[1]*s), packbf(hi[2]*s, hi[3]*s) };
    return __builtin_bit_cast(bf16x8, u);
}
static __device__ __forceinline__ f32x4 mfma16(bf16x8 a, bf16x8 b, f32x4 c) {
    return __builtin_amdgcn_mfma_f32_16x16x32_bf16(a, b, c, 0, 0, 0);
}

// Round-18: hoist stage-invariant LDS reads to registers.
// R6 audit: LDS pipe ~50-55% busy (co-leading with VALU 54%); compiler
// cannot hoist LDS loads across __syncthreads (memory clobber), so a1
// (2 reads/stage), aow (4 reads/stage) were re-read every stage, and the
// k1/k2 RK4 state made an LDS round-trip despite being same-lane data.
// Fix: a1h/a1g built once (8 regs), aow[4] loaded once (16 regs), k1/k2
// in 6 registers; kst buffer deleted (-4 KB LDS). Est. pressure ~95 of
// the 128-total quantum (R2 cliff respected; bias stays in LDS).
// Structure (R16): uniform point id = 16w+m; all 8 waves active in every
// phase; staging fused into out-phase tail; 3 barriers/stage.
__global__ __launch_bounds__(512, 4) void node_rk4_mfma(
    const float* __restrict__ x0,
    const float* __restrict__ h1_w, const float* __restrict__ h1_b,
    const float* __restrict__ g1_w, const float* __restrict__ g1_b,
    const float* __restrict__ h2_w, const float* __restrict__ h2_b,
    const float* __restrict__ g2_w, const float* __restrict__ g2_b,
    const float* __restrict__ out_w, const float* __restrict__ out_b,
    float* __restrict__ y)
{
    extern __shared__ char lds_raw[];
    short*    z1s    = reinterpret_cast<short*>(lds_raw + OFF_Z1);
    short*    z2s    = reinterpret_cast<short*>(lds_raw + OFF_Z2);
    short*    zin    = reinterpret_cast<short*>(lds_raw + OFF_ZIN);
    short*    aow_s  = reinterpret_cast<short*>(lds_raw + OFF_AOW);
    float*    bias_s = reinterpret_cast<float*>(lds_raw + OFF_BIAS);
    unsigned* a1_s   = reinterpret_cast<unsigned*>(lds_raw + OFF_A1);

    const int tid  = threadIdx.x;
    const int w    = tid >> 6;        // wave id 0..7
    const int lane = tid & 63;
    const int q    = lane >> 4;       // quad 0..3
    const int m    = lane & 15;       // MFMA row (A) / col (B,C)

    // ---------------- weight preload (once per block) ----
    const int row = 16 * w + m;                 // lane's A-row (chan) AND point id
    bf16x8 a2h[4], a2g[4];                      // layer2 A-frags per k-step (32 regs)
    sfor<0, 4>([&](auto KS) {
        constexpr int ks = KS.value;
        a2h[ks] = pack8s(h2_w + row * 128 + ks * 32 + q * 8, 1.0f);
        a2g[ks] = pack8s(g2_w + row * 128 + ks * 32 + q * 8, -LOG2E);
    });
    // layer1 A rows -> LDS compact (4 bf16 = 8 B per channel, h then g)
    if (tid < 128) {
        const f32x4 t1 = *reinterpret_cast<const f32x4*>(h1_w + tid * 4);
        const f32x4 t2 = *reinterpret_cast<const f32x4*>(g1_w + tid * 4);
        a1_s[tid * 2]           = packbf(t1[0], t1[1]);
        a1_s[tid * 2 + 1]       = packbf(t1[2], t1[3]);
        a1_s[256 + tid * 2]     = packbf(t2[0] * -LOG2E, t2[1] * -LOG2E);
        a1_s[256 + tid * 2 + 1] = packbf(t2[2] * -LOG2E, t2[3] * -LOG2E);
    }
    // out-layer A-frags -> LDS, compact: only real rows m<3 stored
    if (w == 0 && m < 3) {
        sfor<0, 4>([&](auto KS) {
            constexpr int ks = KS.value;
            bf16x8 t = pack8s(out_w + m * 128 + ks * 32 + q * 8, 2.f * LOG2E);
            *reinterpret_cast<bf16x8*>(&aow_s[((ks * 3 + m) * 4 + q) * 8]) = t;
        });
    }
    // biases -> LDS
    if (tid < 128) {
        bias_s[tid]       = h1_b[tid];
        bias_s[128 + tid] = g1_b[tid] * -LOG2E;
        bias_s[256 + tid] = h2_b[tid];
        bias_s[384 + tid] = g2_b[tid] * -LOG2E;
    }
    if (tid < 16) bias_s[512 + tid] = (tid < 3) ? out_b[tid] * (2.f * LOG2E) : 0.f;

    // zero zin (128 rows): shorts 4..7 of each row must stay 0
    if (tid < 128) *reinterpret_cast<u32x4*>(&zin[tid * 8]) = u32x4{0u, 0u, 0u, 0u};

    const float third = 1.0f / 3.0f;
    const int cb4 = 16 * w + 4 * q;   // this lane's C-frag channel base

    // swizzle helpers (verified R13): (row r, 16B-col c) lives at c ^ (r&7)
    const int m7   = m & 7;
    const int qx8  = (q ^ (m & 3)) * 8;     // q-part of swizzled col, shorts
    const int m4_8 = (m & 4) * 8;           // ks-part toggle, shorts

    // hoisted per-lane LDS base pointers (tile-A bases; tile-B = +const)
    const short* zin_rd = &zin[m * 8];
    short*       zin_wr = &zin[row * 8];                  // lanes<16, all waves
    const short* z1_re  = &z1s[m * Z_S + qx8 + m4_8];
    const short* z1_ro  = &z1s[m * Z_S + qx8 + (m4_8 ^ 32)];
    short*       z1_wr  = &z1s[m * Z_S + (((2 * w + (q >> 1)) ^ m7) * 8) + (q & 1) * 4];
    short*       z2_wr  = &z2s[m * Z_S + (((2 * w + (q >> 1)) ^ m7) * 8) + (q & 1) * 4];
    const short* z2_re  = &z2s[row * Z_S + qx8 + m4_8];       // all waves (rows 0..127)
    const short* z2_ro  = &z2s[row * Z_S + qx8 + (m4_8 ^ 32)];
    const float* bs     = &bias_s[cb4];                   // +0,+128,+256,+384
    const float* bsov   = &bias_s[512 + 4 * q];

    // ---------------- RK4 state: lanes<16 of every wave own point `row` ----
    float xc0 = 0.f, xc1 = 0.f, xc2 = 0.f;
    int gbase = 0;
    if (lane < 16) {
        const int pg = blockIdx.x * 128 + row;
        const int bb = pg / NPT;
        gbase = bb * 3 * NPT + (pg - bb * NPT);
        xc0 = x0[gbase]; xc1 = x0[gbase + NPT]; xc2 = x0[gbase + 2 * NPT];
    }
    float ax = 0.f, ay = 0.f, az = 0.f;
    float k1x = 0.f, k1y = 0.f, k1z = 0.f, k2x = 0.f, k2y = 0.f, k2z = 0.f;

    __syncthreads();   // preload visible to all waves

    // ---- hoisted stage-invariant LDS reads -> registers (R18) ----
    bf16x8 a1h = {0,0,0,0,0,0,0,0}, a1g = {0,0,0,0,0,0,0,0};
    if (q == 0) {
        u32x2 th = *reinterpret_cast<const u32x2*>(&a1_s[row * 2]);
        u32x2 tg = *reinterpret_cast<const u32x2*>(&a1_s[256 + row * 2]);
        u32x4 uh = { th[0], th[1], 0u, 0u };
        u32x4 ug = { tg[0], tg[1], 0u, 0u };
        a1h = __builtin_bit_cast(bf16x8, uh);
        a1g = __builtin_bit_cast(bf16x8, ug);
    }
    bf16x8 aow[4];
    {
        const short* aow_rd = &aow_s[((m < 3 ? m : 2) * 4 + q) * 8];
        sfor<0, 4>([&](auto KS) {
            constexpr int ks = KS.value;
            aow[ks] = *reinterpret_cast<const bf16x8*>(aow_rd + ks * 96);
        });
    }

    // prologue staging: zi = xc, tt = 0
    if (lane < 16) {
        u32x2 pk = { packbf(xc0, xc1), packbf(xc2, 0.f) };
        *reinterpret_cast<u32x2*>(zin_wr) = pk;
    }
    __syncthreads();

    #pragma unroll 1
    for (int s = 0; s < 4; ++s) {
        // ---- layer 1 (4->128), both tiles ----
        {
            const f32x4 b1h = *reinterpret_cast<const f32x4*>(bs);
            const f32x4 b1g = *reinterpret_cast<const f32x4*>(bs + 128);
            sfor<0, 2>([&](auto TT) {
                constexpr int T = TT.value;
                sfor<0, 4>([&](auto NT) {
                    constexpr int nt = NT.value;
                    bf16x8 bf = *reinterpret_cast<const bf16x8*>(zin_rd + T * TBZIN + nt * 128);
                    f32x4 ch = mfma16(a1h, bf, b1h);
                    f32x4 cg = mfma16(a1g, bf, b1g);
                    u32x2 pk = { gate2p(f32x2{ch[0], ch[1]}, f32x2{cg[0], cg[1]}),
                                 gate2p(f32x2{ch[2], ch[3]}, f32x2{cg[2], cg[3]}) };
                    *reinterpret_cast<u32x2*>(z1_wr + T * TBZ + nt * 2048) = pk;
                });
            });
        }
        __syncthreads();

        // ---- layer 2 (128->128), both tiles; nt-pair split keeps acc at 16 ----
        {
            const f32x4 b2h = *reinterpret_cast<const f32x4*>(bs + 256);
            const f32x4 b2g = *reinterpret_cast<const f32x4*>(bs + 384);
            sfor<0, 2>([&](auto TT) {
                constexpr int T = TT.value;
                sfor<0, 2>([&](auto NTP) {
                    constexpr int b0 = T * TBZ + (2 * NTP.value) * 2048;
                    constexpr int b1 = T * TBZ + (2 * NTP.value + 1) * 2048;
                    f32x4 c0h, c1h, c0g, c1g;
                    {
                        bf16x8 f0 = *reinterpret_cast<const bf16x8*>(z1_re + b0);
                        bf16x8 f1 = *reinterpret_cast<const bf16x8*>(z1_re + b1);
                        c0h = mfma16(a2h[0], f0, b2h); c1h = mfma16(a2h[0], f1, b2h);
                        c0g = mfma16(a2g[0], f0, b2g); c1g = mfma16(a2g[0], f1, b2g);
                    }
                    sfor<1, 4>([&](auto KS) {
                        constexpr int ks = KS.value;
                        const short* zb = (ks & 1) ? z1_ro : z1_re;
                        constexpr int koff = (ks & 2) ? 64 : 0;
                        bf16x8 f0 = *reinterpret_cast<const bf16x8*>(zb + b0 + koff);
                        bf16x8 f1 = *reinterpret_cast<const bf16x8*>(zb + b1 + koff);
                        c0h = mfma16(a2h[ks], f0, c0h); c1h = mfma16(a2h[ks], f1, c1h);
                        c0g = mfma16(a2g[ks], f0, c0g); c1g = mfma16(a2g[ks], f1, c1g);
                    });
                    u32x2 pk0 = { gate2p(f32x2{c0h[0], c0h[1]}, f32x2{c0g[0], c0g[1]}),
                                  gate2p(f32x2{c0h[2], c0h[3]}, f32x2{c0g[2], c0g[3]}) };
                    *reinterpret_cast<u32x2*>(z2_wr + b0) = pk0;
                    u32x2 pk1 = { gate2p(f32x2{c1h[0], c1h[1]}, f32x2{c1g[0], c1g[1]}),
                                  gate2p(f32x2{c1h[2], c1h[3]}, f32x2{c1g[2], c1g[3]}) };
                    *reinterpret_cast<u32x2*>(z2_wr + b1) = pk1;
                });
            });
        }
        __syncthreads();

        // ---- out layer (128->3) + FUSED staging; all 8 waves, own 16 pts ----
        {
            f32x4 vc = *reinterpret_cast<const f32x4*>(bsov);
            sfor<0, 4>([&](auto KS) {
                constexpr int ks = KS.value;
                const short* zb = (ks & 1) ? z2_ro : z2_re;
                constexpr int koff = (ks & 2) ? 64 : 0;
                bf16x8 bf = *reinterpret_cast<const bf16x8*>(zb + koff);
                vc = mfma16(aow[ks], bf, vc);
            });
            // khalf = tanh*0.5 = 0.5 - 1/p, p = 2^v' + 1 (scale folded into
            // out weights). Pair kx,ky through one rcp; kz single.
            f32x2 e; e.x = fexp2(vc[0]); e.y = fexp2(vc[1]);
            f32x2 p = e + 1.f;
            const float ipxy = frcp(p.x * p.y);
            const float kx = 0.5f - p.y * ipxy;
            const float ky = 0.5f - p.x * ipxy;
            const float kz = 0.5f - frcp(fexp2(vc[2]) + 1.f);

            if (lane < 16) {
                float zi0, zi1, zi2, tt;
                bool do_stage = true;
                if (s == 0) {
                    ax = kx; ay = ky; az = kz;
                    k1x = kx; k1y = ky; k1z = kz;
                    zi0 = fmaf(kx, third, xc0);
                    zi1 = fmaf(ky, third, xc1);
                    zi2 = fmaf(kz, third, xc2); tt = third;
                } else if (s == 1) {
                    ax = fmaf(3.f, kx, ax); ay = fmaf(3.f, ky, ay); az = fmaf(3.f, kz, az);
                    k2x = kx; k2y = ky; k2z = kz;
                    zi0 = xc0 + (kx - k1x * third);
                    zi1 = xc1 + (ky - k1y * third);
                    zi2 = xc2 + (kz - k1z * third); tt = 2.f * third;
                } else if (s == 2) {
                    ax = fmaf(3.f, kx, ax); ay = fmaf(3.f, ky, ay); az = fmaf(3.f, kz, az);
                    zi0 = xc0 + (k1x - k2x + kx);
                    zi1 = xc1 + (k1y - k2y + ky);
                    zi2 = xc2 + (k1z - k2z + kz); tt = 1.f;
                } else {
                    ax += kx; ay += ky; az += kz;
                    do_stage = false; zi0 = zi1 = zi2 = tt = 0.f;
                }
                if (do_stage) {
                    u32x2 pk = { packbf(zi0, zi1), packbf(zi2, tt) };
                    *reinterpret_cast<u32x2*>(zin_wr) = pk;
                }
            }
        }
        if (s < 3) __syncthreads();
    }

    if (lane < 16) {
        y[gbase]           = fmaf(0.125f, ax, xc0);
        y[gbase + NPT]     = fmaf(0.125f, ay, xc1);
        y[gbase + 2 * NPT] = fmaf(0.125f, az, xc2);
    }
}

extern "C" void kernel_launch(void* const* d_in, const int* in_sizes, int n_in,
                              void* d_out, int out_size, void* d_ws, size_t ws_size,
                              hipStream_t stream) {
    (void)in_sizes; (void)n_in; (void)d_ws; (void)ws_size; (void)out_size;
    const float* x0    = (const float*)d_in[0];
    const float* h1_w  = (const float*)d_in[1];
    const float* h1_b  = (const float*)d_in[2];
    const float* g1_w  = (const float*)d_in[3];
    const float* g1_b  = (const float*)d_in[4];
    const float* h2_w  = (const float*)d_in[5];
    const float* h2_b  = (const float*)d_in[6];
    const float* g2_w  = (const float*)d_in[7];
    const float* g2_b  = (const float*)d_in[8];
    const float* out_w = (const float*)d_in[9];
    const float* out_b = (const float*)d_in[10];
    float* y = (float*)d_out;

    static bool attr_set = false;
    if (!attr_set) {
        (void)hipFuncSetAttribute(reinterpret_cast<const void*>(&node_rk4_mfma),
                                  hipFuncAttributeMaxDynamicSharedMemorySize, LDS_BYTES);
        attr_set = true;
    }
    node_rk4_mfma<<<NBLK, 512, LDS_BYTES, stream>>>(
        x0, h1_w, h1_b, g1_w, g1_b, h2_w, h2_b, g2_w, g2_b, out_w, out_b, y);
}

// Round 11
// 238.913 us; speedup vs baseline: 2.2841x; 1.0121x over previous
//
#include <hip/hip_runtime.h>
#include <math.h>
#include <utility>

typedef __attribute__((ext_vector_type(8))) short    bf16x8;
typedef __attribute__((ext_vector_type(4))) float    f32x4;
typedef __attribute__((ext_vector_type(2))) float    f32x2;
typedef __attribute__((ext_vector_type(2))) unsigned u32x2;
typedef __attribute__((ext_vector_type(4))) unsigned u32x4;

template<int I, int N, class F>
__device__ __forceinline__ void sfor(F&& f) {
    if constexpr (I < N) { f(std::integral_constant<int, I>{}); sfor<I + 1, N>(static_cast<F&&>(f)); }
}

#define NPT    50000
#define NBLK   3125     // 400000 pts / 128 per block (two 64-pt tiles, concurrent)
#define Z_S    128      // shorts per z1/z2 row (256 B), XOR-swizzled 16B columns
#define LOG2E  1.4426950408889634f

// dynamic-LDS byte offsets (all 16B-aligned)
#define OFF_Z1   0        // 128 rows x 128 shorts = 32768 B (tile A rows 0-63, B 64-127)
#define OFF_Z2   32768    // 32768 B
#define OFF_ZIN  65536    // 128 rows x 8 shorts = 2048 B
#define OFF_AOW  67584    // 4*12*8 shorts = 768 B
#define OFF_BIAS 68352    // 528 f32 = 2112 B
#define OFF_A1   70464    // 512 u32 = 2048 B
#define LDS_BYTES 72512
#define TBZ   8192   // tile-B offset in z1/z2, shorts (64 rows)
#define TBZIN 512    // tile-B offset in zin, shorts (64 rows)

// packbf: HW v_cvt_pk_bf16_f32 (R17 win: no builtin on gfx950, inline asm
// required; the SW fallback was ~10 VALU ops and 30% of the VALU pipe).
static __device__ __forceinline__ unsigned packbf(float a, float b) {
    unsigned r;
    asm("v_cvt_pk_bf16_f32 %0, %1, %2" : "=v"(r) : "v"(a), "v"(b));
    return r;   // lo16 = bf16(a), hi16 = bf16(b)
}

#if defined(__has_builtin)
#if __has_builtin(__builtin_amdgcn_exp2f) && __has_builtin(__builtin_amdgcn_rcpf)
#define HAVE_RAW_TRANS 1
#endif
#endif

#ifdef HAVE_RAW_TRANS
static __device__ __forceinline__ float fexp2(float x) { return __builtin_amdgcn_exp2f(x); }
static __device__ __forceinline__ float frcp(float x)  { return __builtin_amdgcn_rcpf(x); }
#else
static __device__ __forceinline__ float fexp2(float x) { return __exp2f(x); }
static __device__ __forceinline__ float frcp(float x)  { return __frcp_rn(x); }
#endif

// gate2p: REVERTED to the R7 compiler-codegen form (199 us, passing).
// ISA ledger from R8-R10 asm attempts: v_pk_add_f32/v_pk_mul_f32 assemble on
// gfx950; v_pk_max_f32 DOES NOT EXIST (pk max is f16/i16 only); hand-written
// VOP3P op_sel produced NaN (likely op_sel_hi default mismatch) — do not
// retry without disasm verification. Compiler output is correct and ~equal.
static __device__ __forceinline__ unsigned gate2p(f32x2 h, f32x2 gp) {
    f32x2 e;
    e.x = fexp2(gp.x);
    e.y = fexp2(gp.y);
    f32x2 p = e + 1.f;
    float ip = frcp(p.x * p.y);
    f32x2 ps = __builtin_shufflevector(p, p, 1, 0);
    f32x2 z = (h * ps) * ip;
    z = __builtin_elementwise_max(z, f32x2{0.f, 0.f});
    return packbf(z.x, z.y);
}

static __device__ __forceinline__ bf16x8 pack8s(const float* p, float s) { // p 16B-aligned
    f32x4 lo = *reinterpret_cast<const f32x4*>(p);
    f32x4 hi = *reinterpret_cast<const f32x4*>(p + 4);
    u32x4 u = { packbf(lo[0]*s, lo[1]*s), packbf(lo[2]*s, lo[3]*s),
                packbf(hi[0]*s, hi[1]*s), packbf(hi[2]*s, hi[3]*s) };
    return __builtin_bit_cast(bf16x8, u);
}
static __device__ __forceinline__ f32x4 mfma16(bf16x8 a, bf16x8 b, f32x4 c) {
    return __builtin_amdgcn_mfma_f32_16x16x32_bf16(a, b, c, 0, 0, 0);
}

// Round-22: FULL UNROLL of the 4-stage RK4 loop (was #pragma unroll 1).
// The per-stage s-conditionals (out-phase tail, staging select) become
// compile-time branches and vanish from the hot path; the compiler sees all
// 12 barrier regions straight-line and can move loads/trans across region
// boundaries it previously couldn't see through the loop back-edge.
// Structure (R16+R18): uniform point id = 16w+m; all 8 waves active in
// every phase; staging fused into out-phase tail; a1/aow/k-state hoisted
// to registers; 3 barriers/stage (structural minimum: three LDS transposes).
__global__ __launch_bounds__(512, 4) void node_rk4_mfma(
    const float* __restrict__ x0,
    const float* __restrict__ h1_w, const float* __restrict__ h1_b,
    const float* __restrict__ g1_w, const float* __restrict__ g1_b,
    const float* __restrict__ h2_w, const float* __restrict__ h2_b,
    const float* __restrict__ g2_w, const float* __restrict__ g2_b,
    const float* __restrict__ out_w, const float* __restrict__ out_b,
    float* __restrict__ y)
{
    extern __shared__ char lds_raw[];
    short*    z1s    = reinterpret_cast<short*>(lds_raw + OFF_Z1);
    short*    z2s    = reinterpret_cast<short*>(lds_raw + OFF_Z2);
    short*    zin    = reinterpret_cast<short*>(lds_raw + OFF_ZIN);
    short*    aow_s  = reinterpret_cast<short*>(lds_raw + OFF_AOW);
    float*    bias_s = reinterpret_cast<float*>(lds_raw + OFF_BIAS);
    unsigned* a1_s   = reinterpret_cast<unsigned*>(lds_raw + OFF_A1);

    const int tid  = threadIdx.x;
    const int w    = tid >> 6;        // wave id 0..7
    const int lane = tid & 63;
    const int q    = lane >> 4;       // quad 0..3
    const int m    = lane & 15;       // MFMA row (A) / col (B,C)

    // ---------------- weight preload (once per block) ----
    const int row = 16 * w + m;                 // lane's A-row (chan) AND point id
    bf16x8 a2h[4], a2g[4];                      // layer2 A-frags per k-step (32 regs)
    sfor<0, 4>([&](auto KS) {
        constexpr int ks = KS.value;
        a2h[ks] = pack8s(h2_w + row * 128 + ks * 32 + q * 8, 1.0f);
        a2g[ks] = pack8s(g2_w + row * 128 + ks * 32 + q * 8, -LOG2E);
    });
    // layer1 A rows -> LDS compact (4 bf16 = 8 B per channel, h then g)
    if (tid < 128) {
        const f32x4 t1 = *reinterpret_cast<const f32x4*>(h1_w + tid * 4);
        const f32x4 t2 = *reinterpret_cast<const f32x4*>(g1_w + tid * 4);
        a1_s[tid * 2]           = packbf(t1[0], t1[1]);
        a1_s[tid * 2 + 1]       = packbf(t1[2], t1[3]);
        a1_s[256 + tid * 2]     = packbf(t2[0] * -LOG2E, t2[1] * -LOG2E);
        a1_s[256 + tid * 2 + 1] = packbf(t2[2] * -LOG2E, t2[3] * -LOG2E);
    }
    // out-layer A-frags -> LDS, compact: only real rows m<3 stored
    if (w == 0 && m < 3) {
        sfor<0, 4>([&](auto KS) {
            constexpr int ks = KS.value;
            bf16x8 t = pack8s(out_w + m * 128 + ks * 32 + q * 8, 2.f * LOG2E);
            *reinterpret_cast<bf16x8*>(&aow_s[((ks * 3 + m) * 4 + q) * 8]) = t;
        });
    }
    // biases -> LDS
    if (tid < 128) {
        bias_s[tid]       = h1_b[tid];
        bias_s[128 + tid] = g1_b[tid] * -LOG2E;
        bias_s[256 + tid] = h2_b[tid];
        bias_s[384 + tid] = g2_b[tid] * -LOG2E;
    }
    if (tid < 16) bias_s[512 + tid] = (tid < 3) ? out_b[tid] * (2.f * LOG2E) : 0.f;

    // zero zin (128 rows): shorts 4..7 of each row must stay 0
    if (tid < 128) *reinterpret_cast<u32x4*>(&zin[tid * 8]) = u32x4{0u, 0u, 0u, 0u};

    const float third = 1.0f / 3.0f;
    const int cb4 = 16 * w + 4 * q;   // this lane's C-frag channel base

    // swizzle helpers (verified R13): (row r, 16B-col c) lives at c ^ (r&7)
    const int m7   = m & 7;
    const int qx8  = (q ^ (m & 3)) * 8;     // q-part of swizzled col, shorts
    const int m4_8 = (m & 4) * 8;           // ks-part toggle, shorts

    // hoisted per-lane LDS base pointers (tile-A bases; tile-B = +const)
    const short* zin_rd = &zin[m * 8];
    short*       zin_wr = &zin[row * 8];                  // lanes<16, all waves
    const short* z1_re  = &z1s[m * Z_S + qx8 + m4_8];
    const short* z1_ro  = &z1s[m * Z_S + qx8 + (m4_8 ^ 32)];
    short*       z1_wr  = &z1s[m * Z_S + (((2 * w + (q >> 1)) ^ m7) * 8) + (q & 1) * 4];
    short*       z2_wr  = &z2s[m * Z_S + (((2 * w + (q >> 1)) ^ m7) * 8) + (q & 1) * 4];
    const short* z2_re  = &z2s[row * Z_S + qx8 + m4_8];       // all waves (rows 0..127)
    const short* z2_ro  = &z2s[row * Z_S + qx8 + (m4_8 ^ 32)];
    const float* bs     = &bias_s[cb4];                   // +0,+128,+256,+384
    const float* bsov   = &bias_s[512 + 4 * q];

    // ---------------- RK4 state: lanes<16 of every wave own point `row` ----
    float xc0 = 0.f, xc1 = 0.f, xc2 = 0.f;
    int gbase = 0;
    if (lane < 16) {
        const int pg = blockIdx.x * 128 + row;
        const int bb = pg / NPT;
        gbase = bb * 3 * NPT + (pg - bb * NPT);
        xc0 = x0[gbase]; xc1 = x0[gbase + NPT]; xc2 = x0[gbase + 2 * NPT];
    }
    float ax = 0.f, ay = 0.f, az = 0.f;
    float k1x = 0.f, k1y = 0.f, k1z = 0.f, k2x = 0.f, k2y = 0.f, k2z = 0.f;

    __syncthreads();   // preload visible to all waves

    // ---- hoisted stage-invariant LDS reads -> registers (R18) ----
    bf16x8 a1h = {0,0,0,0,0,0,0,0}, a1g = {0,0,0,0,0,0,0,0};
    if (q == 0) {
        u32x2 th = *reinterpret_cast<const u32x2*>(&a1_s[row * 2]);
        u32x2 tg = *reinterpret_cast<const u32x2*>(&a1_s[256 + row * 2]);
        u32x4 uh = { th[0], th[1], 0u, 0u };
        u32x4 ug = { tg[0], tg[1], 0u, 0u };
        a1h = __builtin_bit_cast(bf16x8, uh);
        a1g = __builtin_bit_cast(bf16x8, ug);
    }
    bf16x8 aow[4];
    {
        const short* aow_rd = &aow_s[((m < 3 ? m : 2) * 4 + q) * 8];
        sfor<0, 4>([&](auto KS) {
            constexpr int ks = KS.value;
            aow[ks] = *reinterpret_cast<const bf16x8*>(aow_rd + ks * 96);
        });
    }

    // prologue staging: zi = xc, tt = 0
    if (lane < 16) {
        u32x2 pk = { packbf(xc0, xc1), packbf(xc2, 0.f) };
        *reinterpret_cast<u32x2*>(zin_wr) = pk;
    }
    __syncthreads();

    #pragma unroll 4
    for (int s = 0; s < 4; ++s) {
        // ---- layer 1 (4->128), both tiles ----
        {
            const f32x4 b1h = *reinterpret_cast<const f32x4*>(bs);
            const f32x4 b1g = *reinterpret_cast<const f32x4*>(bs + 128);
            sfor<0, 2>([&](auto TT) {
                constexpr int T = TT.value;
                sfor<0, 4>([&](auto NT) {
                    constexpr int nt = NT.value;
                    bf16x8 bf = *reinterpret_cast<const bf16x8*>(zin_rd + T * TBZIN + nt * 128);
                    f32x4 ch = mfma16(a1h, bf, b1h);
                    f32x4 cg = mfma16(a1g, bf, b1g);
                    u32x2 pk = { gate2p(f32x2{ch[0], ch[1]}, f32x2{cg[0], cg[1]}),
                                 gate2p(f32x2{ch[2], ch[3]}, f32x2{cg[2], cg[3]}) };
                    *reinterpret_cast<u32x2*>(z1_wr + T * TBZ + nt * 2048) = pk;
                });
            });
        }
        __syncthreads();

        // ---- layer 2 (128->128), both tiles; nt-pair split keeps acc at 16 ----
        {
            const f32x4 b2h = *reinterpret_cast<const f32x4*>(bs + 256);
            const f32x4 b2g = *reinterpret_cast<const f32x4*>(bs + 384);
            sfor<0, 2>([&](auto TT) {
                constexpr int T = TT.value;
                sfor<0, 2>([&](auto NTP) {
                    constexpr int b0 = T * TBZ + (2 * NTP.value) * 2048;
                    constexpr int b1 = T * TBZ + (2 * NTP.value + 1) * 2048;
                    f32x4 c0h, c1h, c0g, c1g;
                    {
                        bf16x8 f0 = *reinterpret_cast<const bf16x8*>(z1_re + b0);
                        bf16x8 f1 = *reinterpret_cast<const bf16x8*>(z1_re + b1);
                        c0h = mfma16(a2h[0], f0, b2h); c1h = mfma16(a2h[0], f1, b2h);
                        c0g = mfma16(a2g[0], f0, b2g); c1g = mfma16(a2g[0], f1, b2g);
                    }
                    sfor<1, 4>([&](auto KS) {
                        constexpr int ks = KS.value;
                        const short* zb = (ks & 1) ? z1_ro : z1_re;
                        constexpr int koff = (ks & 2) ? 64 : 0;
                        bf16x8 f0 = *reinterpret_cast<const bf16x8*>(zb + b0 + koff);
                        bf16x8 f1 = *reinterpret_cast<const bf16x8*>(zb + b1 + koff);
                        c0h = mfma16(a2h[ks], f0, c0h); c1h = mfma16(a2h[ks], f1, c1h);
                        c0g = mfma16(a2g[ks], f0, c0g); c1g = mfma16(a2g[ks], f1, c1g);
                    });
                    u32x2 pk0 = { gate2p(f32x2{c0h[0], c0h[1]}, f32x2{c0g[0], c0g[1]}),
                                  gate2p(f32x2{c0h[2], c0h[3]}, f32x2{c0g[2], c0g[3]}) };
                    *reinterpret_cast<u32x2*>(z2_wr + b0) = pk0;
                    u32x2 pk1 = { gate2p(f32x2{c1h[0], c1h[1]}, f32x2{c1g[0], c1g[1]}),
                                  gate2p(f32x2{c1h[2], c1h[3]}, f32x2{c1g[2], c1g[3]}) };
                    *reinterpret_cast<u32x2*>(z2_wr + b1) = pk1;
                });
            });
        }
        __syncthreads();

        // ---- out layer (128->3) + FUSED staging; all 8 waves, own 16 pts ----
        {
            f32x4 vc = *reinterpret_cast<const f32x4*>(bsov);
            sfor<0, 4>([&](auto KS) {
                constexpr int ks = KS.value;
                const short* zb = (ks & 1) ? z2_ro : z2_re;
                constexpr int koff = (ks & 2) ? 64 : 0;
                bf16x8 bf = *reinterpret_cast<const bf16x8*>(zb + koff);
                vc = mfma16(aow[ks], bf, vc);
            });
            // khalf = tanh*0.5 = 0.5 - 1/p, p = 2^v' + 1 (scale folded into
            // out weights). Pair kx,ky through one rcp; kz single.
            f32x2 e; e.x = fexp2(vc[0]); e.y = fexp2(vc[1]);
            f32x2 p = e + 1.f;
            const float ipxy = frcp(p.x * p.y);
            const float kx = 0.5f - p.y * ipxy;
            const float ky = 0.5f - p.x * ipxy;
            const float kz = 0.5f - frcp(fexp2(vc[2]) + 1.f);

            if (lane < 16) {
                float zi0, zi1, zi2, tt;
                bool do_stage = true;
                if (s == 0) {
                    ax = kx; ay = ky; az = kz;
                    k1x = kx; k1y = ky; k1z = kz;
                    zi0 = fmaf(kx, third, xc0);
                    zi1 = fmaf(ky, third, xc1);
                    zi2 = fmaf(kz, third, xc2); tt = third;
                } else if (s == 1) {
                    ax = fmaf(3.f, kx, ax); ay = fmaf(3.f, ky, ay); az = fmaf(3.f, kz, az);
                    k2x = kx; k2y = ky; k2z = kz;
                    zi0 = xc0 + (kx - k1x * third);
                    zi1 = xc1 + (ky - k1y * third);
                    zi2 = xc2 + (kz - k1z * third); tt = 2.f * third;
                } else if (s == 2) {
                    ax = fmaf(3.f, kx, ax); ay = fmaf(3.f, ky, ay); az = fmaf(3.f, kz, az);
                    zi0 = xc0 + (k1x - k2x + kx);
                    zi1 = xc1 + (k1y - k2y + ky);
                    zi2 = xc2 + (k1z - k2z + kz); tt = 1.f;
                } else {
                    ax += kx; ay += ky; az += kz;
                    do_stage = false; zi0 = zi1 = zi2 = tt = 0.f;
                }
                if (do_stage) {
                    u32x2 pk = { packbf(zi0, zi1), packbf(zi2, tt) };
                    *reinterpret_cast<u32x2*>(zin_wr) = pk;
                }
            }
        }
        if (s < 3) __syncthreads();
    }

    if (lane < 16) {
        y[gbase]           = fmaf(0.125f, ax, xc0);
        y[gbase + NPT]     = fmaf(0.125f, ay, xc1);
        y[gbase + 2 * NPT] = fmaf(0.125f, az, xc2);
    }
}

extern "C" void kernel_launch(void* const* d_in, const int* in_sizes, int n_in,
                              void* d_out, int out_size, void* d_ws, size_t ws_size,
                              hipStream_t stream) {
    (void)in_sizes; (void)n_in; (void)d_ws; (void)ws_size; (void)out_size;
    const float* x0    = (const float*)d_in[0];
    const float* h1_w  = (const float*)d_in[1];
    const float* h1_b  = (const float*)d_in[2];
    const float* g1_w  = (const float*)d_in[3];
    const float* g1_b  = (const float*)d_in[4];
    const float* h2_w  = (const float*)d_in[5];
    const float* h2_b  = (const float*)d_in[6];
    const float* g2_w  = (const float*)d_in[7];
    const float* g2_b  = (const float*)d_in[8];
    const float* out_w = (const float*)d_in[9];
    const float* out_b = (const float*)d_in[10];
    float* y = (float*)d_out;

    static bool attr_set = false;
    if (!attr_set) {
        (void)hipFuncSetAttribute(reinterpret_cast<const void*>(&node_rk4_mfma),
                                  hipFuncAttributeMaxDynamicSharedMemorySize, LDS_BYTES);
        attr_set = true;
    }
    node_rk4_mfma<<<NBLK, 512, LDS_BYTES, stream>>>(
        x0, h1_w, h1_b, g1_w, g1_b, h2_w, h2_b, g2_w, g2_b, out_w, out_b, y);
}